// Round 9
// baseline (3308.099 us; speedup 1.0000x reference)
//
#include <hip/hip_runtime.h>
#include <hip/hip_bf16.h>
#include <math.h>

typedef __bf16 bf16_t;
typedef __bf16 bf16x8 __attribute__((ext_vector_type(8)));
typedef float  f32x4 __attribute__((ext_vector_type(4)));
typedef float  f4    __attribute__((ext_vector_type(4)));
typedef float  f2    __attribute__((ext_vector_type(2)));
typedef unsigned short u16x4 __attribute__((ext_vector_type(4)));
typedef unsigned long long u64;

#define HS  512
#define BB  128
#define TT  40
#define VV  10000
#define VGGN 4096
#define SLOT ((size_t)65536)   // 128*512
#define NBLK 36                // merged pairs: 36 blocks x 512 threads
#define GRPS 6                 // barrier groups
#define GSZ  6                 // blocks per group
#define ROWP 133               // padded row-dim of LDS acc scratch

// ============================================================================
// Coherent (agent-scope, L2-bypass) accessors — validated rounds 6/8.
// ============================================================================
__device__ __forceinline__ u64 cld64(const void* p) {
  return __hip_atomic_load((const u64*)p, __ATOMIC_RELAXED, __HIP_MEMORY_SCOPE_AGENT);
}
__device__ __forceinline__ void cst64(void* p, u64 v) {
  __hip_atomic_store((u64*)p, v, __ATOMIC_RELAXED, __HIP_MEMORY_SCOPE_AGENT);
}
__device__ __forceinline__ f4 cload_f4(const float* p) {
  f2 lo = __builtin_bit_cast(f2, cld64(p));
  f2 hi = __builtin_bit_cast(f2, cld64(p + 2));
  return f4{lo[0], lo[1], hi[0], hi[1]};
}
__device__ __forceinline__ void cstore_f4(float* p, f4 v) {
  f2 lo = {v[0], v[1]}, hi = {v[2], v[3]};
  cst64(p,     __builtin_bit_cast(u64, lo));
  cst64(p + 2, __builtin_bit_cast(u64, hi));
}
__device__ __forceinline__ u64 pack_bf4(f4 v) {
  u16x4 r;
  r[0] = __builtin_bit_cast(unsigned short, (bf16_t)v[0]);
  r[1] = __builtin_bit_cast(unsigned short, (bf16_t)v[1]);
  r[2] = __builtin_bit_cast(unsigned short, (bf16_t)v[2]);
  r[3] = __builtin_bit_cast(unsigned short, (bf16_t)v[3]);
  return __builtin_bit_cast(u64, r);
}
__device__ __forceinline__ bf16x8 cload_bf8(const bf16_t* p) {
  f2 lo = __builtin_bit_cast(f2, cld64(p));
  f2 hi = __builtin_bit_cast(f2, cld64(p + 4));
  f4 t = {lo[0], lo[1], hi[0], hi[1]};
  return __builtin_bit_cast(bf16x8, t);
}

// ============================================================================
// Hierarchical line-padded grid barrier, SYMMETRIC waiting (round-8 protocol,
// validated; alignment invariant requires every block to wait each barrier).
// 36 blocks = 6 groups x 6. grpCnt[g]@g*64, rootCnt@512, grpGen[g]@(9+g)*64.
// ============================================================================
__device__ __forceinline__ void gbar(unsigned* sync, unsigned idx)
{
  __syncthreads();                 // per-wave vmcnt(0) drain: stores ACKed @L3
  asm volatile("" ::: "memory");
  if (threadIdx.x == 0) {
    const int g = blockIdx.x / GSZ;
    unsigned a = __hip_atomic_fetch_add(&sync[g * 64], 1u,
                                        __ATOMIC_RELAXED, __HIP_MEMORY_SCOPE_AGENT);
    if ((a + 1u) % GSZ == 0u) {
      unsigned r = __hip_atomic_fetch_add(&sync[512], 1u,
                                          __ATOMIC_RELAXED, __HIP_MEMORY_SCOPE_AGENT);
      if ((r + 1u) % GRPS == 0u) {
        unsigned k = (r + 1u) / GRPS;
#pragma unroll
        for (int j = 0; j < GRPS; ++j)
          __hip_atomic_store(&sync[(9 + j) * 64], k,
                             __ATOMIC_RELAXED, __HIP_MEMORY_SCOPE_AGENT);
      }
    }
    while (__hip_atomic_load(&sync[(9 + (int)(blockIdx.x / GSZ)) * 64],
                             __ATOMIC_RELAXED, __HIP_MEMORY_SCOPE_AGENT) <= idx)
      __builtin_amdgcn_s_sleep(8);
  }
  asm volatile("" ::: "memory");
  __syncthreads();
}

__global__ void zero_sync(unsigned* p)
{
  for (int i = threadIdx.x; i < 2048; i += 256) p[i] = 0u;
}

// ============================================================================
// Batched MFMA GEMM: C[M,N] = A[M,512] @ Bt[N,512]^T (+bias), fp32 out.
// ============================================================================
__global__ __launch_bounds__(256) void gemm_bt(
    const bf16_t* __restrict__ A, const bf16_t* __restrict__ Bt,
    const float* __restrict__ bias, float* __restrict__ C,
    int Nvalid, int ldc, int permute_tb)
{
  const int bm = blockIdx.x * 128, bn = blockIdx.y * 128;
  const int tid = threadIdx.x;
  const int wave = tid >> 6, lane = tid & 63;
  const int wm = (wave >> 1) * 64, wn = (wave & 1) * 64;
  const int l15 = lane & 15, kg = lane >> 4;
  const bf16_t* Ap = A + (size_t)(bm + wm + l15) * 512 + kg * 8;
  const bf16_t* Bp = Bt + (size_t)(bn + wn + l15) * 512 + kg * 8;
  f32x4 acc[4][4];
#pragma unroll
  for (int i = 0; i < 4; ++i)
#pragma unroll
    for (int j = 0; j < 4; ++j)
#pragma unroll
      for (int e = 0; e < 4; ++e) acc[i][j][e] = 0.f;

  for (int kk = 0; kk < 512; kk += 32) {
    bf16x8 a[4], b[4];
#pragma unroll
    for (int i = 0; i < 4; ++i) a[i] = *(const bf16x8*)(Ap + (size_t)i * 16 * 512 + kk);
#pragma unroll
    for (int j = 0; j < 4; ++j) b[j] = *(const bf16x8*)(Bp + (size_t)j * 16 * 512 + kk);
#pragma unroll
    for (int i = 0; i < 4; ++i)
#pragma unroll
      for (int j = 0; j < 4; ++j)
        acc[i][j] = __builtin_amdgcn_mfma_f32_16x16x32_bf16(a[i], b[j], acc[i][j], 0, 0, 0);
  }

#pragma unroll
  for (int fm = 0; fm < 4; ++fm) {
#pragma unroll
    for (int fn = 0; fn < 4; ++fn) {
      int n = bn + wn + fn * 16 + l15;
      if (n >= Nvalid) continue;
      float bv = bias ? bias[n] : 0.f;
#pragma unroll
      for (int e = 0; e < 4; ++e) {
        int m = bm + wm + fm * 16 + kg * 4 + e;
        int orow = permute_tb ? ((m & 127) * TT + (m >> 7)) : m;
        C[(size_t)orow * ldc + n] = acc[fm][fn][e] + bv;
      }
    }
  }
}

// ============================================================================
// Persistent GRU recurrence — 36 blocks x 512 threads (merged old pairs).
// half = wave>>2 selects the old-block identity ob = 2*bid + half; role
// boundaries (16/48/56) are even so both halves share one role & branch path.
// Old role map (per ob): [0,16) RU-L0 K=512; [16,48) RU-L1 K=1024;
// [48,56) C-L0 K=512; [56,72) C-L1 K=1024.
// Stage s: phase RU ; gbar(2s) ; phase C ; gbar(2s+1).  (round-8 flow)
// A-panel coherent loads are depth-4 software-pipelined (atomics keep source
// order, so issuing 4 steps ahead guarantees 6-8 loads in flight).
// ============================================================================
struct PArgs {
  const bf16_t *Btru0, *Bt1ru, *Btc0, *Btc1;
  const float  *xg0, *bu, *br, *bc;
  bf16_t *hb0_seq, *hb1_seq, *rh0, *rh1;
  float  *hs0, *hs1, *u0, *u1;
  unsigned *sync;
};

template<int K>
__device__ __forceinline__ void tile_gemm(
    const bf16_t* __restrict__ A0, const bf16_t* __restrict__ A1,
    const bf16_t* BsH, int wave, int lane, f32x4 (&acc)[2][4])
{
  constexpr int NF = (K == 512) ? 4 : 2;
  constexpr int NS = K / 32;
  const int l15 = lane & 15, kg = lane >> 4;
  const int mw = (wave & 3) * 32;
#pragma unroll
  for (int i = 0; i < 2; ++i)
#pragma unroll
    for (int f = 0; f < 4; ++f)
#pragma unroll
      for (int e = 0; e < 4; ++e) acc[i][f][e] = 0.f;

  bf16x8 a[4][2];
  auto aload = [&](int step, int slot) {
    const bf16_t* Asrc = (step * 32 < 512) ? A0 : A1;
    const int kc = ((step * 32) & 511) + kg * 8;
    a[slot][0] = cload_bf8(Asrc + (size_t)(mw + l15) * 512 + kc);
    a[slot][1] = cload_bf8(Asrc + (size_t)(mw + 16 + l15) * 512 + kc);
  };
  aload(0, 0); aload(1, 1); aload(2, 2); aload(3, 3);

#pragma unroll
  for (int s = 0; s < NS; ++s) {
    bf16x8 b[NF];
#pragma unroll
    for (int f = 0; f < NF; ++f) {
      int row = f * 16 + l15;
      int byteoff = row * (2 * K) + ((64 * s + 16 * kg) ^ ((row & 7) << 4));
      b[f] = *(const bf16x8*)((const char*)BsH + byteoff);
    }
    const int slot = s & 3;
#pragma unroll
    for (int i = 0; i < 2; ++i)
#pragma unroll
      for (int f = 0; f < NF; ++f)
        acc[i][f] = __builtin_amdgcn_mfma_f32_16x16x32_bf16(a[slot][i], b[f], acc[i][f], 0, 0, 0);
    if (s + 4 < NS) aload(s + 4, slot);
  }
}

__global__ __launch_bounds__(512, 2) void gru_persist(PArgs P)
{
  const int bid = blockIdx.x, tid = threadIdx.x;
  const int wave = tid >> 6, lane = tid & 63;
  const int half = wave >> 2;
  const int tid4 = tid & 255;
  const int ob   = bid * 2 + half;
  const int l15 = lane & 15, kg = lane >> 4;
  const int mw = (wave & 3) * 32;
  unsigned* sync = P.sync;

  int role, q;
  if (ob < 16)      { role = 0; q = ob; }
  else if (ob < 48) { role = 1; q = ob - 16; }
  else if (ob < 56) { role = 2; q = ob - 48; }
  else              { role = 3; q = ob - 56; }
  const int K  = (role == 0 || role == 2) ? 512 : 1024;
  const int NT = (K == 512) ? 64 : 32;
  const int tileBase = q * NT;

  const bf16_t* Wsrc =
      role == 0 ? P.Btru0 + (size_t)tileBase * 512 :
      role == 1 ? P.Bt1ru + (size_t)tileBase * 1024 :
      role == 2 ? P.Btc0  + (size_t)tileBase * 512 :
                  P.Btc1  + (size_t)tileBase * 1024;

  __shared__ bf16_t Bs[2][32768];        // 128 KB: one 64 KB weight tile/half
  __shared__ float  accs[2][16 * ROWP];  // 2 x 8.3 KB epilogue scratch
  bf16_t* BsH  = Bs[half];
  float* accsH = accs[half];
  {
    const int rsh = (K == 512) ? 10 : 11;
    const int rmask = 2 * K - 1;
#pragma unroll
    for (int it = 0; it < 16; ++it) {
      int ofs = (it * 256 + tid4) * 16;
      int row = ofs >> rsh, cb = ofs & rmask;
      *(f4*)((char*)BsH + row * 2 * K + (cb ^ ((row & 7) << 4))) =
          *(const f4*)((const char*)Wsrc + ofs);
    }
  }
  __syncthreads();

  // epilogue mapping: 16-col passes; thread covers cols c4p..+4, rows r0,r0+64
  const int c4p = (tid4 & 3) * 4;
  const int r0  = tid4 >> 2;            // 0..63

  for (int s = 0; s <= 40; ++s) {
    // ---------------- phase RU ----------------
    if (role == 0 && s < 40) {
      f32x4 acc[2][4];
      const bf16_t* A0 = P.hb0_seq + (size_t)s * SLOT;
      tile_gemm<512>(A0, A0, BsH, wave, lane, acc);
      const float* xg = P.xg0 + (size_t)s * 128 * 1536;
      const bool ublock = (tileBase < 512);
      const int n0 = ublock ? tileBase : tileBase - 512;
#pragma unroll
      for (int f = 0; f < 4; ++f) {
#pragma unroll
        for (int i = 0; i < 2; ++i)
#pragma unroll
          for (int e = 0; e < 4; ++e)
            accsH[l15 * ROWP + (mw + i * 16 + kg * 4 + e)] = acc[i][f][e];
        __syncthreads();
#pragma unroll
        for (int p = 0; p < 2; ++p) {
          int row = r0 + p * 64;
          int cg16 = f * 16 + c4p;                 // col within this block's NT=64
          f4 aa;
#pragma unroll
          for (int cc = 0; cc < 4; ++cc) aa[cc] = accsH[(c4p + cc) * ROWP + row];
          f4 xv = *(const f4*)&xg[(size_t)row * 1536 + tileBase + cg16];
          f4 sg;
#pragma unroll
          for (int cc = 0; cc < 4; ++cc) sg[cc] = 1.f / (1.f + expf(-(aa[cc] + xv[cc])));
          int nn = n0 + cg16;
          if (ublock) {
            cstore_f4(&P.u0[row * 512 + nn], sg);
          } else {
            f4 h = cload_f4(&P.hs0[row * 512 + nn]);
            cst64(&P.rh0[row * 512 + nn], pack_bf4(sg * h));
          }
        }
        __syncthreads();
      }
    } else if (role == 1 && s >= 1) {
      f32x4 acc[2][4];
      tile_gemm<1024>(P.hb0_seq + (size_t)s * SLOT,
                      P.hb1_seq + (size_t)(s - 1) * SLOT,
                      BsH, wave, lane, acc);
      const bool ublock = (tileBase < 512);
      const int n0 = ublock ? tileBase : tileBase - 512;
      const float* bias = ublock ? (P.bu + 512 + tileBase) : (P.br + tileBase);
#pragma unroll
      for (int f = 0; f < 2; ++f) {
#pragma unroll
        for (int i = 0; i < 2; ++i)
#pragma unroll
          for (int e = 0; e < 4; ++e)
            accsH[l15 * ROWP + (mw + i * 16 + kg * 4 + e)] = acc[i][f][e];
        __syncthreads();
#pragma unroll
        for (int p = 0; p < 2; ++p) {
          int row = r0 + p * 64;
          int cg16 = f * 16 + c4p;                 // col within NT=32
          f4 aa;
#pragma unroll
          for (int cc = 0; cc < 4; ++cc) aa[cc] = accsH[(c4p + cc) * ROWP + row];
          f4 bv = *(const f4*)&bias[cg16];
          f4 sg;
#pragma unroll
          for (int cc = 0; cc < 4; ++cc) sg[cc] = 1.f / (1.f + expf(-(aa[cc] + bv[cc])));
          int nn = n0 + cg16;
          if (ublock) {
            cstore_f4(&P.u1[row * 512 + nn], sg);
          } else {
            f4 h = cload_f4(&P.hs1[row * 512 + nn]);
            cst64(&P.rh1[row * 512 + nn], pack_bf4(sg * h));
          }
        }
        __syncthreads();
      }
    }
    gbar(sync, 2 * s);
    // ---------------- phase C ----------------
    if (role == 2 && s < 40) {
      f32x4 acc[2][4];
      tile_gemm<512>(P.rh0, P.rh0, BsH, wave, lane, acc);
      const float* xg = P.xg0 + (size_t)s * 128 * 1536;
#pragma unroll
      for (int f = 0; f < 4; ++f) {
#pragma unroll
        for (int i = 0; i < 2; ++i)
#pragma unroll
          for (int e = 0; e < 4; ++e)
            accsH[l15 * ROWP + (mw + i * 16 + kg * 4 + e)] = acc[i][f][e];
        __syncthreads();
#pragma unroll
        for (int p = 0; p < 2; ++p) {
          int row = r0 + p * 64;
          int n = tileBase + f * 16 + c4p;
          f4 aa;
#pragma unroll
          for (int cc = 0; cc < 4; ++cc) aa[cc] = accsH[(c4p + cc) * ROWP + row];
          f4 xv = *(const f4*)&xg[(size_t)row * 1536 + 1024 + n];
          f4 cg;
#pragma unroll
          for (int cc = 0; cc < 4; ++cc) cg[cc] = tanhf(aa[cc] + xv[cc]);
          f4 u = cload_f4(&P.u0[row * 512 + n]);
          f4 h = cload_f4(&P.hs0[row * 512 + n]);
          f4 hn = u * h + (f4{1.f,1.f,1.f,1.f} - u) * cg;
          cstore_f4(&P.hs0[row * 512 + n], hn);
          cst64(&P.hb0_seq[(size_t)(s + 1) * SLOT + row * 512 + n], pack_bf4(hn));
        }
        __syncthreads();
      }
    } else if (role == 3 && s >= 1) {
      f32x4 acc[2][4];
      tile_gemm<1024>(P.hb0_seq + (size_t)s * SLOT, P.rh1,
                      BsH, wave, lane, acc);
#pragma unroll
      for (int f = 0; f < 2; ++f) {
#pragma unroll
        for (int i = 0; i < 2; ++i)
#pragma unroll
          for (int e = 0; e < 4; ++e)
            accsH[l15 * ROWP + (mw + i * 16 + kg * 4 + e)] = acc[i][f][e];
        __syncthreads();
#pragma unroll
        for (int p = 0; p < 2; ++p) {
          int row = r0 + p * 64;
          int n = tileBase + f * 16 + c4p;
          f4 aa;
#pragma unroll
          for (int cc = 0; cc < 4; ++cc) aa[cc] = accsH[(c4p + cc) * ROWP + row];
          f4 bv = *(const f4*)&P.bc[512 + n];
          f4 cg;
#pragma unroll
          for (int cc = 0; cc < 4; ++cc) cg[cc] = tanhf(aa[cc] + bv[cc]);
          f4 u = cload_f4(&P.u1[row * 512 + n]);
          f4 h = cload_f4(&P.hs1[row * 512 + n]);
          f4 hn = u * h + (f4{1.f,1.f,1.f,1.f} - u) * cg;
          cstore_f4(&P.hs1[row * 512 + n], hn);
          cst64(&P.hb1_seq[(size_t)s * SLOT + row * 512 + n], pack_bf4(hn));
        }
        __syncthreads();
      }
    }
    gbar(sync, 2 * s + 1);
  }
}

// ============================================================================
// h0 = tanh(vgg @ W_in + b_in) via bf16 MFMA, split-K=8.
// ============================================================================
__global__ __launch_bounds__(256) void h0_gemm(
    const bf16_t* __restrict__ vggb, const bf16_t* __restrict__ Wint,
    float* __restrict__ part)
{
  const int bn = blockIdx.x * 128, z = blockIdx.y, k0 = z * 512;
  const int tid = threadIdx.x;
  const int wave = tid >> 6, lane = tid & 63;
  const int wm = (wave >> 1) * 64, wn = (wave & 1) * 64;
  const int l15 = lane & 15, kg = lane >> 4;
  const bf16_t* Ap = vggb + (size_t)(wm + l15) * 4096 + k0 + kg * 8;
  const bf16_t* Bp = Wint + (size_t)(bn + wn + l15) * 4096 + k0 + kg * 8;
  f32x4 acc[4][4];
#pragma unroll
  for (int i = 0; i < 4; ++i)
#pragma unroll
    for (int j = 0; j < 4; ++j)
#pragma unroll
      for (int e = 0; e < 4; ++e) acc[i][j][e] = 0.f;
  for (int kk = 0; kk < 512; kk += 32) {
    bf16x8 a[4], b[4];
#pragma unroll
    for (int i = 0; i < 4; ++i) a[i] = *(const bf16x8*)(Ap + (size_t)i * 16 * 4096 + kk);
#pragma unroll
    for (int j = 0; j < 4; ++j) b[j] = *(const bf16x8*)(Bp + (size_t)j * 16 * 4096 + kk);
#pragma unroll
    for (int i = 0; i < 4; ++i)
#pragma unroll
      for (int j = 0; j < 4; ++j)
        acc[i][j] = __builtin_amdgcn_mfma_f32_16x16x32_bf16(a[i], b[j], acc[i][j], 0, 0, 0);
  }
#pragma unroll
  for (int fm = 0; fm < 4; ++fm)
#pragma unroll
    for (int fn = 0; fn < 4; ++fn) {
      int n = bn + wn + fn * 16 + l15;
#pragma unroll
      for (int e = 0; e < 4; ++e) {
        int m = wm + fm * 16 + kg * 4 + e;
        part[(size_t)z * SLOT + m * 512 + n] = acc[fm][fn][e];
      }
    }
}

__global__ void h0_fin(const float* __restrict__ part, const float* __restrict__ bin,
                       float* __restrict__ hs0, float* __restrict__ hs1,
                       bf16_t* __restrict__ hb00, bf16_t* __restrict__ hb10)
{
  int i = blockIdx.x * 256 + threadIdx.x;   // 65536
  int n = i & 511;
  float s = bin[n];
#pragma unroll
  for (int z = 0; z < 8; ++z) s += part[(size_t)z * SLOT + i];
  float v = tanhf(s);
  hs0[i] = v; hs1[i] = v;
  hb00[i] = (bf16_t)v; hb10[i] = (bf16_t)v;
}

__global__ void conv_bf16(const float* __restrict__ src, bf16_t* __restrict__ dst)
{
  int i = blockIdx.x * 256 + threadIdx.x;
  f4 v = ((const f4*)src)[i];
  dst[i * 4 + 0] = (bf16_t)v[0]; dst[i * 4 + 1] = (bf16_t)v[1];
  dst[i * 4 + 2] = (bf16_t)v[2]; dst[i * 4 + 3] = (bf16_t)v[3];
}

__global__ void gather_emb(const int* __restrict__ tok, const float* __restrict__ emb,
                           bf16_t* __restrict__ A)
{
  int m = blockIdx.x;
  int t = m >> 7, b = m & 127;
  int tk = tok[b * TT + t];
  const float* src = emb + (size_t)tk * 512;
  int i = threadIdx.x;
  f4 v = *(const f4*)(src + i * 4);
  bf16_t* dst = A + (size_t)m * 512 + i * 4;
  dst[0] = (bf16_t)v[0]; dst[1] = (bf16_t)v[1];
  dst[2] = (bf16_t)v[2]; dst[3] = (bf16_t)v[3];
}

struct TJob { const float* src; bf16_t* dst; int K; int dstld; };
struct TJobs10 { TJob j[10]; };
__global__ void transpose_gen(TJobs10 jobs)
{
  TJob jb = jobs.j[blockIdx.z];
  int k0 = blockIdx.x * 32;
  if (k0 >= jb.K) return;
  int n0 = blockIdx.y * 32;
  __shared__ float tile[32][33];
  int tx = threadIdx.x, ty = threadIdx.y;
#pragma unroll
  for (int r = 0; r < 4; ++r)
    tile[ty + 8 * r][tx] = jb.src[(size_t)(k0 + ty + 8 * r) * 512 + n0 + tx];
  __syncthreads();
#pragma unroll
  for (int r = 0; r < 4; ++r)
    jb.dst[(size_t)(n0 + ty + 8 * r) * jb.dstld + k0 + tx] = (bf16_t)tile[tx][ty + 8 * r];
}

__global__ void transpose_wout(const float* __restrict__ W, bf16_t* __restrict__ dst)
{
  __shared__ float tile[32][33];
  int k0 = blockIdx.x * 32, n0 = blockIdx.y * 32;
  int tx = threadIdx.x, ty = threadIdx.y;
#pragma unroll
  for (int r = 0; r < 4; ++r) {
    int n = n0 + tx;
    tile[ty + 8 * r][tx] = (n < VV) ? W[(size_t)(k0 + ty + 8 * r) * VV + n] : 0.f;
  }
  __syncthreads();
#pragma unroll
  for (int r = 0; r < 4; ++r)
    dst[(size_t)(n0 + ty + 8 * r) * 512 + k0 + tx] = (bf16_t)tile[tx][ty + 8 * r];
}

__global__ void build_xbias(const float* __restrict__ bu, const float* __restrict__ br,
                            const float* __restrict__ bc, float* __restrict__ xb)
{
  int i = blockIdx.x * 256 + threadIdx.x;
  if (i < 2 * 1536) {
    int j = i / 1536, qq = i % 1536;
    int g = qq >> 9, n = qq & 511;
    const float* src = (g == 0) ? bu : (g == 1) ? br : bc;
    xb[i] = src[j * 512 + n];
  }
}

__global__ void write_hfinal(const float* __restrict__ hs0_last,
                             const float* __restrict__ hs1_last,
                             float* __restrict__ out)
{
  int i = blockIdx.x * 256 + threadIdx.x;
  out[i] = hs0_last[i];
  out[65536 + i] = hs1_last[i];
}

// ============================================================================
extern "C" void kernel_launch(void* const* d_in, const int* in_sizes, int n_in,
                              void* d_out, int out_size, void* d_ws, size_t ws_size,
                              hipStream_t stream)
{
  const int*   tok = (const int*)  d_in[0];
  const float* vgg = (const float*)d_in[1];
  const float* emb = (const float*)d_in[2];
  const float* Win = (const float*)d_in[3];
  const float* bin = (const float*)d_in[4];
  const float* Wu  = (const float*)d_in[5];
  const float* bu  = (const float*)d_in[6];
  const float* Wr  = (const float*)d_in[7];
  const float* br  = (const float*)d_in[8];
  const float* Wc  = (const float*)d_in[9];
  const float* bc  = (const float*)d_in[10];
  const float* Wo  = (const float*)d_in[11];
  const float* bo  = (const float*)d_in[12];
  float* out = (float*)d_out;

  size_t off = 0;
  auto alloc = [&](size_t bytes) -> void* {
    void* p = (char*)d_ws + off;
    off += (bytes + 255) & ~(size_t)255;
    return p;
  };
  float*  hs0   = (float*) alloc(SLOT * 4);
  float*  hs1   = (float*) alloc(SLOT * 4);
  float*  u0    = (float*) alloc(SLOT * 4);
  float*  u1    = (float*) alloc(SLOT * 4);
  bf16_t* rh0   = (bf16_t*)alloc(SLOT * 2);
  bf16_t* rh1   = (bf16_t*)alloc(SLOT * 2);
  bf16_t* hb0_seq = (bf16_t*)alloc(41 * SLOT * 2);
  bf16_t* hb1_seq = (bf16_t*)alloc(41 * SLOT * 2);
  bf16_t* Aemb  = (bf16_t*)alloc((size_t)TT * BB * 512 * 2);
  float*  xg0   = (float*) alloc((size_t)TT * BB * 1536 * 4);
  bf16_t* Btx0  = (bf16_t*)alloc((size_t)1536 * 512 * 2);
  bf16_t* Btru0 = (bf16_t*)alloc((size_t)1024 * 512 * 2);
  bf16_t* Btc0  = (bf16_t*)alloc((size_t)512 * 512 * 2);
  bf16_t* Bt1ru = (bf16_t*)alloc((size_t)1024 * 1024 * 2);
  bf16_t* Btc1  = (bf16_t*)alloc((size_t)512 * 1024 * 2);
  bf16_t* Wto   = (bf16_t*)alloc((size_t)10112 * 512 * 2);
  bf16_t* Wint  = (bf16_t*)alloc((size_t)512 * 4096 * 2);
  bf16_t* vggb  = (bf16_t*)alloc((size_t)128 * 4096 * 2);
  float*  h0part= (float*) alloc(8 * SLOT * 4);
  float*  xbias = (float*) alloc(2 * 1536 * 4);
  unsigned* syncws = (unsigned*) alloc(8192);
  if (off > ws_size) return;

  TJobs10 tj;
  tj.j[0] = { Wu,                Btx0,                512, 512 };
  tj.j[1] = { Wr,                Btx0 + 262144,       512, 512 };
  tj.j[2] = { Wc,                Btx0 + 524288,       512, 512 };
  tj.j[3] = { Wu + 262144,       Btru0,               512, 512 };
  tj.j[4] = { Wr + 262144,       Btru0 + 262144,      512, 512 };
  tj.j[5] = { Wc + 262144,       Btc0,                512, 512 };
  tj.j[6] = { Wu + 524288,       Bt1ru,               1024, 1024 };
  tj.j[7] = { Wr + 524288,       Bt1ru + 524288,      1024, 1024 };
  tj.j[8] = { Wc + 524288,       Btc1,                1024, 1024 };
  tj.j[9] = { Win,               Wint,                4096, 4096 };
  transpose_gen<<<dim3(128, 16, 10), dim3(32, 8), 0, stream>>>(tj);
  transpose_wout<<<dim3(16, 316), dim3(32, 8), 0, stream>>>(Wo, Wto);
  build_xbias<<<12, 256, 0, stream>>>(bu, br, bc, xbias);
  gather_emb<<<TT * BB, 128, 0, stream>>>(tok, emb, Aemb);
  conv_bf16<<<512, 256, 0, stream>>>(vgg, vggb);
  zero_sync<<<1, 256, 0, stream>>>(syncws);

  h0_gemm<<<dim3(4, 8), 256, 0, stream>>>(vggb, Wint, h0part);
  h0_fin<<<256, 256, 0, stream>>>(h0part, bin, hs0, hs1, hb0_seq, hb1_seq);

  gemm_bt<<<dim3(40, 12), 256, 0, stream>>>(Aemb, Btx0, xbias, xg0, 1536, 1536, 0);

  PArgs pa;
  pa.Btru0 = Btru0; pa.Bt1ru = Bt1ru; pa.Btc0 = Btc0; pa.Btc1 = Btc1;
  pa.xg0 = xg0; pa.bu = bu; pa.br = br; pa.bc = bc;
  pa.hb0_seq = hb0_seq; pa.hb1_seq = hb1_seq;
  pa.rh0 = rh0; pa.rh1 = rh1;
  pa.hs0 = hs0; pa.hs1 = hs1; pa.u0 = u0; pa.u1 = u1;
  pa.sync = syncws;
  gru_persist<<<NBLK, 512, 0, stream>>>(pa);

  gemm_bt<<<dim3(40, 79), 256, 0, stream>>>(hb1_seq + SLOT, Wto, bo, out, VV, VV, 1);

  write_hfinal<<<256, 256, 0, stream>>>(hs0, hs1, out + (size_t)BB * TT * VV);
}

// Round 10
// 1980.838 us; speedup vs baseline: 1.6701x; 1.6701x over previous
//
#include <hip/hip_runtime.h>
#include <hip/hip_bf16.h>
#include <math.h>

typedef __bf16 bf16_t;
typedef __bf16 bf16x8 __attribute__((ext_vector_type(8)));
typedef float  f32x4 __attribute__((ext_vector_type(4)));
typedef float  f4    __attribute__((ext_vector_type(4)));
typedef float  f2    __attribute__((ext_vector_type(2)));
typedef unsigned short u16x4 __attribute__((ext_vector_type(4)));
typedef unsigned long long u64;

#define HS  512
#define BB  128
#define TT  40
#define VV  10000
#define VGGN 4096
#define SLOT ((size_t)65536)   // 128*512
#define NBLK 72
#define GRPS 8                 // barrier groups
#define GSZ  9                 // blocks per group
#define ROWP 133               // padded row-dim of LDS acc scratch

// ============================================================================
// Coherent (agent-scope, L2-bypass) accessors — validated rounds 6/8.
// ============================================================================
__device__ __forceinline__ u64 cld64(const void* p) {
  return __hip_atomic_load((const u64*)p, __ATOMIC_RELAXED, __HIP_MEMORY_SCOPE_AGENT);
}
__device__ __forceinline__ void cst64(void* p, u64 v) {
  __hip_atomic_store((u64*)p, v, __ATOMIC_RELAXED, __HIP_MEMORY_SCOPE_AGENT);
}
__device__ __forceinline__ f4 cload_f4(const float* p) {
  f2 lo = __builtin_bit_cast(f2, cld64(p));
  f2 hi = __builtin_bit_cast(f2, cld64(p + 2));
  return f4{lo[0], lo[1], hi[0], hi[1]};
}
__device__ __forceinline__ void cstore_f4(float* p, f4 v) {
  f2 lo = {v[0], v[1]}, hi = {v[2], v[3]};
  cst64(p,     __builtin_bit_cast(u64, lo));
  cst64(p + 2, __builtin_bit_cast(u64, hi));
}
__device__ __forceinline__ u64 pack_bf4(f4 v) {
  u16x4 r;
  r[0] = __builtin_bit_cast(unsigned short, (bf16_t)v[0]);
  r[1] = __builtin_bit_cast(unsigned short, (bf16_t)v[1]);
  r[2] = __builtin_bit_cast(unsigned short, (bf16_t)v[2]);
  r[3] = __builtin_bit_cast(unsigned short, (bf16_t)v[3]);
  return __builtin_bit_cast(u64, r);
}
__device__ __forceinline__ bf16x8 cload_bf8(const bf16_t* p) {
  f2 lo = __builtin_bit_cast(f2, cld64(p));
  f2 hi = __builtin_bit_cast(f2, cld64(p + 4));
  f4 t = {lo[0], lo[1], hi[0], hi[1]};
  return __builtin_bit_cast(bf16x8, t);
}

// ============================================================================
// Hierarchical line-padded grid barrier, SYMMETRIC waiting (round-8 protocol,
// validated). grpCnt[g]@g*64, rootCnt@512, grpGen[g]@(9+g)*64.
// ============================================================================
__device__ __forceinline__ void gbar(unsigned* sync, unsigned idx)
{
  __syncthreads();                 // per-wave vmcnt(0) drain: stores ACKed @L3
  asm volatile("" ::: "memory");
  if (threadIdx.x == 0) {
    const int g = blockIdx.x / GSZ;
    unsigned a = __hip_atomic_fetch_add(&sync[g * 64], 1u,
                                        __ATOMIC_RELAXED, __HIP_MEMORY_SCOPE_AGENT);
    if ((a + 1u) % GSZ == 0u) {
      unsigned r = __hip_atomic_fetch_add(&sync[512], 1u,
                                          __ATOMIC_RELAXED, __HIP_MEMORY_SCOPE_AGENT);
      if ((r + 1u) % GRPS == 0u) {
        unsigned k = (r + 1u) / GRPS;
#pragma unroll
        for (int j = 0; j < GRPS; ++j)
          __hip_atomic_store(&sync[(9 + j) * 64], k,
                             __ATOMIC_RELAXED, __HIP_MEMORY_SCOPE_AGENT);
      }
    }
    while (__hip_atomic_load(&sync[(9 + g) * 64],
                             __ATOMIC_RELAXED, __HIP_MEMORY_SCOPE_AGENT) <= idx)
      __builtin_amdgcn_s_sleep(8);
  }
  asm volatile("" ::: "memory");
  __syncthreads();
}

__global__ void zero_sync(unsigned* p)
{
  for (int i = threadIdx.x; i < 2048; i += 256) p[i] = 0u;
}

// ============================================================================
// Batched MFMA GEMM: C[M,N] = A[M,512] @ Bt[N,512]^T (+bias), fp32 out.
// ============================================================================
__global__ __launch_bounds__(256) void gemm_bt(
    const bf16_t* __restrict__ A, const bf16_t* __restrict__ Bt,
    const float* __restrict__ bias, float* __restrict__ C,
    int Nvalid, int ldc, int permute_tb)
{
  const int bm = blockIdx.x * 128, bn = blockIdx.y * 128;
  const int tid = threadIdx.x;
  const int wave = tid >> 6, lane = tid & 63;
  const int wm = (wave >> 1) * 64, wn = (wave & 1) * 64;
  const int l15 = lane & 15, kg = lane >> 4;
  const bf16_t* Ap = A + (size_t)(bm + wm + l15) * 512 + kg * 8;
  const bf16_t* Bp = Bt + (size_t)(bn + wn + l15) * 512 + kg * 8;
  f32x4 acc[4][4];
#pragma unroll
  for (int i = 0; i < 4; ++i)
#pragma unroll
    for (int j = 0; j < 4; ++j)
#pragma unroll
      for (int e = 0; e < 4; ++e) acc[i][j][e] = 0.f;

  for (int kk = 0; kk < 512; kk += 32) {
    bf16x8 a[4], b[4];
#pragma unroll
    for (int i = 0; i < 4; ++i) a[i] = *(const bf16x8*)(Ap + (size_t)i * 16 * 512 + kk);
#pragma unroll
    for (int j = 0; j < 4; ++j) b[j] = *(const bf16x8*)(Bp + (size_t)j * 16 * 512 + kk);
#pragma unroll
    for (int i = 0; i < 4; ++i)
#pragma unroll
      for (int j = 0; j < 4; ++j)
        acc[i][j] = __builtin_amdgcn_mfma_f32_16x16x32_bf16(a[i], b[j], acc[i][j], 0, 0, 0);
  }

#pragma unroll
  for (int fm = 0; fm < 4; ++fm) {
#pragma unroll
    for (int fn = 0; fn < 4; ++fn) {
      int n = bn + wn + fn * 16 + l15;
      if (n >= Nvalid) continue;
      float bv = bias ? bias[n] : 0.f;
#pragma unroll
      for (int e = 0; e < 4; ++e) {
        int m = bm + wm + fm * 16 + kg * 4 + e;
        int orow = permute_tb ? ((m & 127) * TT + (m >> 7)) : m;
        C[(size_t)orow * ldc + n] = acc[fm][fn][e] + bv;
      }
    }
  }
}

// ============================================================================
// Persistent GRU recurrence — round-8 structure exactly, with two latency
// fixes: (1) tile_gemm issues ALL coherent A-loads per 512-K half up front
// (1 block/CU -> VGPR headroom is free; exposure ~1-2 L3 latencies instead
// of 16 chained groups); (2) epilogue u/hs coherent loads are issued BEFORE
// tile_gemm (addresses independent of GEMM output; producers published at
// the previous barrier; WAR-safe: same thread reads then writes).
// Roles: [0,16) RU-L0 K=512 ; [16,48) RU-L1 K=1024 ; [48,56) C-L0 K=512 ;
// [56,72) C-L1 K=1024.  Stage s: RU ; gbar(2s) ; C ; gbar(2s+1).
// ============================================================================
struct PArgs {
  const bf16_t *Btru0, *Bt1ru, *Btc0, *Btc1;
  const float  *xg0, *bu, *br, *bc;
  bf16_t *hb0_seq, *hb1_seq, *rh0, *rh1;
  float  *hs0, *hs1, *u0, *u1;
  unsigned *sync;
};

template<int K>
__device__ __forceinline__ void tile_gemm(
    const bf16_t* __restrict__ A0, const bf16_t* __restrict__ A1,
    const bf16_t* Bs, int wave, int lane, f32x4 (&acc)[2][4])
{
  constexpr int NF = (K == 512) ? 4 : 2;
  const int l15 = lane & 15, kg = lane >> 4;
  const int mw = wave * 32;
#pragma unroll
  for (int i = 0; i < 2; ++i)
#pragma unroll
    for (int f = 0; f < 4; ++f)
#pragma unroll
      for (int e = 0; e < 4; ++e) acc[i][f][e] = 0.f;

  const bf16_t* srcs[2] = {A0, A1};
#pragma unroll
  for (int h = 0; h < K / 512; ++h) {
    const bf16_t* Asrc = srcs[h];
    bf16x8 a[16][2];
#pragma unroll
    for (int s = 0; s < 16; ++s) {           // batch-issue ALL 32 loads
      int kc = s * 32 + kg * 8;
      a[s][0] = cload_bf8(Asrc + (size_t)(mw + l15) * 512 + kc);
      a[s][1] = cload_bf8(Asrc + (size_t)(mw + 16 + l15) * 512 + kc);
    }
#pragma unroll
    for (int s = 0; s < 16; ++s) {
      int kk = h * 512 + s * 32;
      bf16x8 b[NF];
#pragma unroll
      for (int f = 0; f < NF; ++f) {
        int row = f * 16 + l15;
        int byteoff = row * (2 * K) + ((2 * kk + 16 * kg) ^ ((row & 7) << 4));
        b[f] = *(const bf16x8*)((const char*)Bs + byteoff);
      }
#pragma unroll
      for (int i = 0; i < 2; ++i)
#pragma unroll
        for (int f = 0; f < NF; ++f)
          acc[i][f] = __builtin_amdgcn_mfma_f32_16x16x32_bf16(a[s][i], b[f], acc[i][f], 0, 0, 0);
    }
  }
}

// Stage acc fragments into LDS scratch: accs[col][ROWP] (col-major, padded).
template<int NF>
__device__ __forceinline__ void stage_acc(float* accs, f32x4 (&acc)[2][4],
                                          int wave, int lane)
{
  const int l15 = lane & 15, kg = lane >> 4;
  const int mw = wave * 32;
#pragma unroll
  for (int i = 0; i < 2; ++i)
#pragma unroll
    for (int f = 0; f < NF; ++f)
#pragma unroll
      for (int e = 0; e < 4; ++e)
        accs[(f * 16 + l15) * ROWP + (mw + i * 16 + kg * 4 + e)] = acc[i][f][e];
}

__global__ __launch_bounds__(256) void gru_persist(PArgs P)
{
  const int bid = blockIdx.x, tid = threadIdx.x;
  const int wave = tid >> 6, lane = tid & 63;
  unsigned* sync = P.sync;

  int role, q;
  if (bid < 16)      { role = 0; q = bid; }
  else if (bid < 48) { role = 1; q = bid - 16; }
  else if (bid < 56) { role = 2; q = bid - 48; }
  else               { role = 3; q = bid - 56; }
  const int K  = (role == 0 || role == 2) ? 512 : 1024;
  const int NT = (K == 512) ? 64 : 32;
  const int tileBase = q * NT;

  const bf16_t* Wsrc =
      role == 0 ? P.Btru0 + (size_t)tileBase * 512 :
      role == 1 ? P.Bt1ru + (size_t)tileBase * 1024 :
      role == 2 ? P.Btc0  + (size_t)tileBase * 512 :
                  P.Btc1  + (size_t)tileBase * 1024;

  __shared__ bf16_t Bs[32768];          // 64 KB weight tile (swizzled)
  __shared__ float  accs[64 * ROWP];    // 34 KB epilogue transpose scratch
  {
    const int rsh = (K == 512) ? 10 : 11;
    const int rmask = 2 * K - 1;
#pragma unroll
    for (int it = 0; it < 16; ++it) {
      int ofs = (it * 256 + tid) * 16;
      int row = ofs >> rsh, cb = ofs & rmask;
      *(f4*)((char*)Bs + row * 2 * K + (cb ^ ((row & 7) << 4))) =
          *(const f4*)((const char*)Wsrc + ofs);
    }
  }
  __syncthreads();

  // epilogue mapping constants
  const int c4w = (tid & 15) * 4, r0w = tid >> 4;   // 64-col roles
  const int c4n = (tid & 7) * 4,  r0n = tid >> 3;   // 32-col roles

  for (int s = 0; s <= 40; ++s) {
    // ---------------- phase RU ----------------
    if (role == 0 && s < 40) {
      const bool ublock = (tileBase < 512);
      const int n0 = ublock ? tileBase : tileBase - 512;
      f4 hpre[8];
      if (!ublock) {
#pragma unroll
        for (int p = 0; p < 8; ++p)
          hpre[p] = cload_f4(&P.hs0[(r0w + p * 16) * 512 + n0 + c4w]);
      }
      f32x4 acc[2][4];
      const bf16_t* A0 = P.hb0_seq + (size_t)s * SLOT;
      tile_gemm<512>(A0, A0, Bs, wave, lane, acc);
      stage_acc<4>(accs, acc, wave, lane);
      __syncthreads();
      const float* xg = P.xg0 + (size_t)s * 128 * 1536;
#pragma unroll
      for (int p = 0; p < 8; ++p) {
        int row = r0w + p * 16;
        f4 a;
#pragma unroll
        for (int cc = 0; cc < 4; ++cc) a[cc] = accs[(c4w + cc) * ROWP + row];
        f4 xv = *(const f4*)&xg[(size_t)row * 1536 + tileBase + c4w];
        f4 sg;
#pragma unroll
        for (int cc = 0; cc < 4; ++cc) sg[cc] = 1.f / (1.f + expf(-(a[cc] + xv[cc])));
        if (ublock) {
          cstore_f4(&P.u0[row * 512 + n0 + c4w], sg);
        } else {
          cst64(&P.rh0[row * 512 + n0 + c4w], pack_bf4(sg * hpre[p]));
        }
      }
    } else if (role == 1 && s >= 1) {
      const bool ublock = (tileBase < 512);
      const int n0 = ublock ? tileBase : tileBase - 512;
      f4 hpre[4];
      if (!ublock) {
#pragma unroll
        for (int p = 0; p < 4; ++p)
          hpre[p] = cload_f4(&P.hs1[(r0n + p * 32) * 512 + n0 + c4n]);
      }
      f32x4 acc[2][4];
      tile_gemm<1024>(P.hb0_seq + (size_t)s * SLOT,
                      P.hb1_seq + (size_t)(s - 1) * SLOT,
                      Bs, wave, lane, acc);
      stage_acc<2>(accs, acc, wave, lane);
      __syncthreads();
      const float* bias = ublock ? (P.bu + 512 + tileBase) : (P.br + tileBase);
#pragma unroll
      for (int p = 0; p < 4; ++p) {
        int row = r0n + p * 32;
        f4 a;
#pragma unroll
        for (int cc = 0; cc < 4; ++cc) a[cc] = accs[(c4n + cc) * ROWP + row];
        f4 bv = *(const f4*)&bias[c4n];
        f4 sg;
#pragma unroll
        for (int cc = 0; cc < 4; ++cc) sg[cc] = 1.f / (1.f + expf(-(a[cc] + bv[cc])));
        if (ublock) {
          cstore_f4(&P.u1[row * 512 + n0 + c4n], sg);
        } else {
          cst64(&P.rh1[row * 512 + n0 + c4n], pack_bf4(sg * hpre[p]));
        }
      }
    }
    gbar(sync, 2 * s);
    // ---------------- phase C ----------------
    if (role == 2 && s < 40) {
      f4 upre[8], hpre[8];
#pragma unroll
      for (int p = 0; p < 8; ++p) {
        int row = r0w + p * 16;
        int n = tileBase + c4w;
        upre[p] = cload_f4(&P.u0[row * 512 + n]);
        hpre[p] = cload_f4(&P.hs0[row * 512 + n]);
      }
      f32x4 acc[2][4];
      tile_gemm<512>(P.rh0, P.rh0, Bs, wave, lane, acc);
      stage_acc<4>(accs, acc, wave, lane);
      __syncthreads();
      const float* xg = P.xg0 + (size_t)s * 128 * 1536;
#pragma unroll
      for (int p = 0; p < 8; ++p) {
        int row = r0w + p * 16;
        int n = tileBase + c4w;
        f4 a;
#pragma unroll
        for (int cc = 0; cc < 4; ++cc) a[cc] = accs[(c4w + cc) * ROWP + row];
        f4 xv = *(const f4*)&xg[(size_t)row * 1536 + 1024 + n];
        f4 cg;
#pragma unroll
        for (int cc = 0; cc < 4; ++cc) cg[cc] = tanhf(a[cc] + xv[cc]);
        f4 hn = upre[p] * hpre[p] + (f4{1.f,1.f,1.f,1.f} - upre[p]) * cg;
        cstore_f4(&P.hs0[row * 512 + n], hn);
        cst64(&P.hb0_seq[(size_t)(s + 1) * SLOT + row * 512 + n], pack_bf4(hn));
      }
    } else if (role == 3 && s >= 1) {
      f4 upre[4], hpre[4];
#pragma unroll
      for (int p = 0; p < 4; ++p) {
        int row = r0n + p * 32;
        int n = tileBase + c4n;
        upre[p] = cload_f4(&P.u1[row * 512 + n]);
        hpre[p] = cload_f4(&P.hs1[row * 512 + n]);
      }
      f32x4 acc[2][4];
      tile_gemm<1024>(P.hb0_seq + (size_t)s * SLOT, P.rh1,
                      Bs, wave, lane, acc);
      stage_acc<2>(accs, acc, wave, lane);
      __syncthreads();
#pragma unroll
      for (int p = 0; p < 4; ++p) {
        int row = r0n + p * 32;
        int n = tileBase + c4n;
        f4 a;
#pragma unroll
        for (int cc = 0; cc < 4; ++cc) a[cc] = accs[(c4n + cc) * ROWP + row];
        f4 bv = *(const f4*)&P.bc[512 + n];
        f4 cg;
#pragma unroll
        for (int cc = 0; cc < 4; ++cc) cg[cc] = tanhf(a[cc] + bv[cc]);
        f4 hn = upre[p] * hpre[p] + (f4{1.f,1.f,1.f,1.f} - upre[p]) * cg;
        cstore_f4(&P.hs1[row * 512 + n], hn);
        cst64(&P.hb1_seq[(size_t)s * SLOT + row * 512 + n], pack_bf4(hn));
      }
    }
    gbar(sync, 2 * s + 1);
  }
}

// ============================================================================
// h0 = tanh(vgg @ W_in + b_in) via bf16 MFMA, split-K=8.
// ============================================================================
__global__ __launch_bounds__(256) void h0_gemm(
    const bf16_t* __restrict__ vggb, const bf16_t* __restrict__ Wint,
    float* __restrict__ part)
{
  const int bn = blockIdx.x * 128, z = blockIdx.y, k0 = z * 512;
  const int tid = threadIdx.x;
  const int wave = tid >> 6, lane = tid & 63;
  const int wm = (wave >> 1) * 64, wn = (wave & 1) * 64;
  const int l15 = lane & 15, kg = lane >> 4;
  const bf16_t* Ap = vggb + (size_t)(wm + l15) * 4096 + k0 + kg * 8;
  const bf16_t* Bp = Wint + (size_t)(bn + wn + l15) * 4096 + k0 + kg * 8;
  f32x4 acc[4][4];
#pragma unroll
  for (int i = 0; i < 4; ++i)
#pragma unroll
    for (int j = 0; j < 4; ++j)
#pragma unroll
      for (int e = 0; e < 4; ++e) acc[i][j][e] = 0.f;
  for (int kk = 0; kk < 512; kk += 32) {
    bf16x8 a[4], b[4];
#pragma unroll
    for (int i = 0; i < 4; ++i) a[i] = *(const bf16x8*)(Ap + (size_t)i * 16 * 4096 + kk);
#pragma unroll
    for (int j = 0; j < 4; ++j) b[j] = *(const bf16x8*)(Bp + (size_t)j * 16 * 4096 + kk);
#pragma unroll
    for (int i = 0; i < 4; ++i)
#pragma unroll
      for (int j = 0; j < 4; ++j)
        acc[i][j] = __builtin_amdgcn_mfma_f32_16x16x32_bf16(a[i], b[j], acc[i][j], 0, 0, 0);
  }
#pragma unroll
  for (int fm = 0; fm < 4; ++fm)
#pragma unroll
    for (int fn = 0; fn < 4; ++fn) {
      int n = bn + wn + fn * 16 + l15;
#pragma unroll
      for (int e = 0; e < 4; ++e) {
        int m = wm + fm * 16 + kg * 4 + e;
        part[(size_t)z * SLOT + m * 512 + n] = acc[fm][fn][e];
      }
    }
}

__global__ void h0_fin(const float* __restrict__ part, const float* __restrict__ bin,
                       float* __restrict__ hs0, float* __restrict__ hs1,
                       bf16_t* __restrict__ hb00, bf16_t* __restrict__ hb10)
{
  int i = blockIdx.x * 256 + threadIdx.x;   // 65536
  int n = i & 511;
  float s = bin[n];
#pragma unroll
  for (int z = 0; z < 8; ++z) s += part[(size_t)z * SLOT + i];
  float v = tanhf(s);
  hs0[i] = v; hs1[i] = v;
  hb00[i] = (bf16_t)v; hb10[i] = (bf16_t)v;
}

__global__ void conv_bf16(const float* __restrict__ src, bf16_t* __restrict__ dst)
{
  int i = blockIdx.x * 256 + threadIdx.x;
  f4 v = ((const f4*)src)[i];
  dst[i * 4 + 0] = (bf16_t)v[0]; dst[i * 4 + 1] = (bf16_t)v[1];
  dst[i * 4 + 2] = (bf16_t)v[2]; dst[i * 4 + 3] = (bf16_t)v[3];
}

__global__ void gather_emb(const int* __restrict__ tok, const float* __restrict__ emb,
                           bf16_t* __restrict__ A)
{
  int m = blockIdx.x;
  int t = m >> 7, b = m & 127;
  int tk = tok[b * TT + t];
  const float* src = emb + (size_t)tk * 512;
  int i = threadIdx.x;
  f4 v = *(const f4*)(src + i * 4);
  bf16_t* dst = A + (size_t)m * 512 + i * 4;
  dst[0] = (bf16_t)v[0]; dst[1] = (bf16_t)v[1];
  dst[2] = (bf16_t)v[2]; dst[3] = (bf16_t)v[3];
}

struct TJob { const float* src; bf16_t* dst; int K; int dstld; };
struct TJobs10 { TJob j[10]; };
__global__ void transpose_gen(TJobs10 jobs)
{
  TJob jb = jobs.j[blockIdx.z];
  int k0 = blockIdx.x * 32;
  if (k0 >= jb.K) return;
  int n0 = blockIdx.y * 32;
  __shared__ float tile[32][33];
  int tx = threadIdx.x, ty = threadIdx.y;
#pragma unroll
  for (int r = 0; r < 4; ++r)
    tile[ty + 8 * r][tx] = jb.src[(size_t)(k0 + ty + 8 * r) * 512 + n0 + tx];
  __syncthreads();
#pragma unroll
  for (int r = 0; r < 4; ++r)
    jb.dst[(size_t)(n0 + ty + 8 * r) * jb.dstld + k0 + tx] = (bf16_t)tile[tx][ty + 8 * r];
}

__global__ void transpose_wout(const float* __restrict__ W, bf16_t* __restrict__ dst)
{
  __shared__ float tile[32][33];
  int k0 = blockIdx.x * 32, n0 = blockIdx.y * 32;
  int tx = threadIdx.x, ty = threadIdx.y;
#pragma unroll
  for (int r = 0; r < 4; ++r) {
    int n = n0 + tx;
    tile[ty + 8 * r][tx] = (n < VV) ? W[(size_t)(k0 + ty + 8 * r) * VV + n] : 0.f;
  }
  __syncthreads();
#pragma unroll
  for (int r = 0; r < 4; ++r)
    dst[(size_t)(n0 + ty + 8 * r) * 512 + k0 + tx] = (bf16_t)tile[tx][ty + 8 * r];
}

__global__ void build_xbias(const float* __restrict__ bu, const float* __restrict__ br,
                            const float* __restrict__ bc, float* __restrict__ xb)
{
  int i = blockIdx.x * 256 + threadIdx.x;
  if (i < 2 * 1536) {
    int j = i / 1536, qq = i % 1536;
    int g = qq >> 9, n = qq & 511;
    const float* src = (g == 0) ? bu : (g == 1) ? br : bc;
    xb[i] = src[j * 512 + n];
  }
}

__global__ void write_hfinal(const float* __restrict__ hs0_last,
                             const float* __restrict__ hs1_last,
                             float* __restrict__ out)
{
  int i = blockIdx.x * 256 + threadIdx.x;
  out[i] = hs0_last[i];
  out[65536 + i] = hs1_last[i];
}

// ============================================================================
extern "C" void kernel_launch(void* const* d_in, const int* in_sizes, int n_in,
                              void* d_out, int out_size, void* d_ws, size_t ws_size,
                              hipStream_t stream)
{
  const int*   tok = (const int*)  d_in[0];
  const float* vgg = (const float*)d_in[1];
  const float* emb = (const float*)d_in[2];
  const float* Win = (const float*)d_in[3];
  const float* bin = (const float*)d_in[4];
  const float* Wu  = (const float*)d_in[5];
  const float* bu  = (const float*)d_in[6];
  const float* Wr  = (const float*)d_in[7];
  const float* br  = (const float*)d_in[8];
  const float* Wc  = (const float*)d_in[9];
  const float* bc  = (const float*)d_in[10];
  const float* Wo  = (const float*)d_in[11];
  const float* bo  = (const float*)d_in[12];
  float* out = (float*)d_out;

  size_t off = 0;
  auto alloc = [&](size_t bytes) -> void* {
    void* p = (char*)d_ws + off;
    off += (bytes + 255) & ~(size_t)255;
    return p;
  };
  float*  hs0   = (float*) alloc(SLOT * 4);
  float*  hs1   = (float*) alloc(SLOT * 4);
  float*  u0    = (float*) alloc(SLOT * 4);
  float*  u1    = (float*) alloc(SLOT * 4);
  bf16_t* rh0   = (bf16_t*)alloc(SLOT * 2);
  bf16_t* rh1   = (bf16_t*)alloc(SLOT * 2);
  bf16_t* hb0_seq = (bf16_t*)alloc(41 * SLOT * 2);
  bf16_t* hb1_seq = (bf16_t*)alloc(41 * SLOT * 2);
  bf16_t* Aemb  = (bf16_t*)alloc((size_t)TT * BB * 512 * 2);
  float*  xg0   = (float*) alloc((size_t)TT * BB * 1536 * 4);
  bf16_t* Btx0  = (bf16_t*)alloc((size_t)1536 * 512 * 2);
  bf16_t* Btru0 = (bf16_t*)alloc((size_t)1024 * 512 * 2);
  bf16_t* Btc0  = (bf16_t*)alloc((size_t)512 * 512 * 2);
  bf16_t* Bt1ru = (bf16_t*)alloc((size_t)1024 * 1024 * 2);
  bf16_t* Btc1  = (bf16_t*)alloc((size_t)512 * 1024 * 2);
  bf16_t* Wto   = (bf16_t*)alloc((size_t)10112 * 512 * 2);
  bf16_t* Wint  = (bf16_t*)alloc((size_t)512 * 4096 * 2);
  bf16_t* vggb  = (bf16_t*)alloc((size_t)128 * 4096 * 2);
  float*  h0part= (float*) alloc(8 * SLOT * 4);
  float*  xbias = (float*) alloc(2 * 1536 * 4);
  unsigned* syncws = (unsigned*) alloc(8192);
  if (off > ws_size) return;

  TJobs10 tj;
  tj.j[0] = { Wu,                Btx0,                512, 512 };
  tj.j[1] = { Wr,                Btx0 + 262144,       512, 512 };
  tj.j[2] = { Wc,                Btx0 + 524288,       512, 512 };
  tj.j[3] = { Wu + 262144,       Btru0,               512, 512 };
  tj.j[4] = { Wr + 262144,       Btru0 + 262144,      512, 512 };
  tj.j[5] = { Wc + 262144,       Btc0,                512, 512 };
  tj.j[6] = { Wu + 524288,       Bt1ru,               1024, 1024 };
  tj.j[7] = { Wr + 524288,       Bt1ru + 524288,      1024, 1024 };
  tj.j[8] = { Wc + 524288,       Btc1,                1024, 1024 };
  tj.j[9] = { Win,               Wint,                4096, 4096 };
  transpose_gen<<<dim3(128, 16, 10), dim3(32, 8), 0, stream>>>(tj);
  transpose_wout<<<dim3(16, 316), dim3(32, 8), 0, stream>>>(Wo, Wto);
  build_xbias<<<12, 256, 0, stream>>>(bu, br, bc, xbias);
  gather_emb<<<TT * BB, 128, 0, stream>>>(tok, emb, Aemb);
  conv_bf16<<<512, 256, 0, stream>>>(vgg, vggb);
  zero_sync<<<1, 256, 0, stream>>>(syncws);

  h0_gemm<<<dim3(4, 8), 256, 0, stream>>>(vggb, Wint, h0part);
  h0_fin<<<256, 256, 0, stream>>>(h0part, bin, hs0, hs1, hb0_seq, hb1_seq);

  gemm_bt<<<dim3(40, 12), 256, 0, stream>>>(Aemb, Btx0, xbias, xg0, 1536, 1536, 0);

  PArgs pa;
  pa.Btru0 = Btru0; pa.Bt1ru = Bt1ru; pa.Btc0 = Btc0; pa.Btc1 = Btc1;
  pa.xg0 = xg0; pa.bu = bu; pa.br = br; pa.bc = bc;
  pa.hb0_seq = hb0_seq; pa.hb1_seq = hb1_seq;
  pa.rh0 = rh0; pa.rh1 = rh1;
  pa.hs0 = hs0; pa.hs1 = hs1; pa.u0 = u0; pa.u1 = u1;
  pa.sync = syncws;
  gru_persist<<<NBLK, 256, 0, stream>>>(pa);

  gemm_bt<<<dim3(40, 79), 256, 0, stream>>>(hb1_seq + SLOT, Wto, bo, out, VV, VV, 1);

  write_hfinal<<<256, 256, 0, stream>>>(hs0, hs1, out + (size_t)BB * TT * VV);
}

// Round 11
// 1696.299 us; speedup vs baseline: 1.9502x; 1.1677x over previous
//
#include <hip/hip_runtime.h>
#include <hip/hip_bf16.h>
#include <math.h>

typedef __bf16 bf16_t;
typedef __bf16 bf16x8 __attribute__((ext_vector_type(8)));
typedef float  f32x4 __attribute__((ext_vector_type(4)));
typedef float  f4    __attribute__((ext_vector_type(4)));
typedef float  f2    __attribute__((ext_vector_type(2)));
typedef unsigned short u16x4 __attribute__((ext_vector_type(4)));
typedef unsigned long long u64;

#define HS  512
#define BB  128
#define TT  40
#define VV  10000
#define VGGN 4096
#define SLOT ((size_t)65536)   // 128*512
#define NBLK 72                // persistent recurrence blocks
#define NGRID 256              // total blocks (72 persist + 184 logits workers)
#define GRPS 8                 // barrier groups (persist blocks only)
#define GSZ  9                 // blocks per group
#define ROWP 133               // padded row-dim of LDS acc scratch

// ============================================================================
// Coherent (agent-scope, L2-bypass) accessors — validated rounds 6/8.
// ============================================================================
__device__ __forceinline__ u64 cld64(const void* p) {
  return __hip_atomic_load((const u64*)p, __ATOMIC_RELAXED, __HIP_MEMORY_SCOPE_AGENT);
}
__device__ __forceinline__ void cst64(void* p, u64 v) {
  __hip_atomic_store((u64*)p, v, __ATOMIC_RELAXED, __HIP_MEMORY_SCOPE_AGENT);
}
__device__ __forceinline__ f4 cload_f4(const float* p) {
  f2 lo = __builtin_bit_cast(f2, cld64(p));
  f2 hi = __builtin_bit_cast(f2, cld64(p + 2));
  return f4{lo[0], lo[1], hi[0], hi[1]};
}
__device__ __forceinline__ void cstore_f4(float* p, f4 v) {
  f2 lo = {v[0], v[1]}, hi = {v[2], v[3]};
  cst64(p,     __builtin_bit_cast(u64, lo));
  cst64(p + 2, __builtin_bit_cast(u64, hi));
}
__device__ __forceinline__ u64 pack_bf4(f4 v) {
  u16x4 r;
  r[0] = __builtin_bit_cast(unsigned short, (bf16_t)v[0]);
  r[1] = __builtin_bit_cast(unsigned short, (bf16_t)v[1]);
  r[2] = __builtin_bit_cast(unsigned short, (bf16_t)v[2]);
  r[3] = __builtin_bit_cast(unsigned short, (bf16_t)v[3]);
  return __builtin_bit_cast(u64, r);
}
__device__ __forceinline__ bf16x8 cload_bf8(const bf16_t* p) {
  f2 lo = __builtin_bit_cast(f2, cld64(p));
  f2 hi = __builtin_bit_cast(f2, cld64(p + 4));
  f4 t = {lo[0], lo[1], hi[0], hi[1]};
  return __builtin_bit_cast(bf16x8, t);
}

// ============================================================================
// Hierarchical line-padded grid barrier, SYMMETRIC waiting (round-8 protocol,
// validated). Only the 72 persist blocks arrive/wait. Workers read grpGen
// lines (read-only) to learn publication progress.
// grpCnt[g]@g*64, rootCnt@512, grpGen[g]@(9+g)*64.
// ============================================================================
__device__ __forceinline__ void gbar(unsigned* sync, unsigned idx)
{
  __syncthreads();                 // per-wave vmcnt(0) drain: stores ACKed @L3
  asm volatile("" ::: "memory");
  if (threadIdx.x == 0) {
    const int g = blockIdx.x / GSZ;
    unsigned a = __hip_atomic_fetch_add(&sync[g * 64], 1u,
                                        __ATOMIC_RELAXED, __HIP_MEMORY_SCOPE_AGENT);
    if ((a + 1u) % GSZ == 0u) {
      unsigned r = __hip_atomic_fetch_add(&sync[512], 1u,
                                          __ATOMIC_RELAXED, __HIP_MEMORY_SCOPE_AGENT);
      if ((r + 1u) % GRPS == 0u) {
        unsigned k = (r + 1u) / GRPS;
#pragma unroll
        for (int j = 0; j < GRPS; ++j)
          __hip_atomic_store(&sync[(9 + j) * 64], k,
                             __ATOMIC_RELAXED, __HIP_MEMORY_SCOPE_AGENT);
      }
    }
    while (__hip_atomic_load(&sync[(9 + g) * 64],
                             __ATOMIC_RELAXED, __HIP_MEMORY_SCOPE_AGENT) <= idx)
      __builtin_amdgcn_s_sleep(8);
  }
  asm volatile("" ::: "memory");
  __syncthreads();
}

__global__ void zero_sync(unsigned* p)
{
  for (int i = threadIdx.x; i < 2048; i += 256) p[i] = 0u;
}

// ============================================================================
// Batched MFMA GEMM: C[M,N] = A[M,512] @ Bt[N,512]^T (+bias), fp32 out.
// (still used for the xg0 pass)
// ============================================================================
__global__ __launch_bounds__(256) void gemm_bt(
    const bf16_t* __restrict__ A, const bf16_t* __restrict__ Bt,
    const float* __restrict__ bias, float* __restrict__ C,
    int Nvalid, int ldc, int permute_tb)
{
  const int bm = blockIdx.x * 128, bn = blockIdx.y * 128;
  const int tid = threadIdx.x;
  const int wave = tid >> 6, lane = tid & 63;
  const int wm = (wave >> 1) * 64, wn = (wave & 1) * 64;
  const int l15 = lane & 15, kg = lane >> 4;
  const bf16_t* Ap = A + (size_t)(bm + wm + l15) * 512 + kg * 8;
  const bf16_t* Bp = Bt + (size_t)(bn + wn + l15) * 512 + kg * 8;
  f32x4 acc[4][4];
#pragma unroll
  for (int i = 0; i < 4; ++i)
#pragma unroll
    for (int j = 0; j < 4; ++j)
#pragma unroll
      for (int e = 0; e < 4; ++e) acc[i][j][e] = 0.f;

  for (int kk = 0; kk < 512; kk += 32) {
    bf16x8 a[4], b[4];
#pragma unroll
    for (int i = 0; i < 4; ++i) a[i] = *(const bf16x8*)(Ap + (size_t)i * 16 * 512 + kk);
#pragma unroll
    for (int j = 0; j < 4; ++j) b[j] = *(const bf16x8*)(Bp + (size_t)j * 16 * 512 + kk);
#pragma unroll
    for (int i = 0; i < 4; ++i)
#pragma unroll
      for (int j = 0; j < 4; ++j)
        acc[i][j] = __builtin_amdgcn_mfma_f32_16x16x32_bf16(a[i], b[j], acc[i][j], 0, 0, 0);
  }

#pragma unroll
  for (int fm = 0; fm < 4; ++fm) {
#pragma unroll
    for (int fn = 0; fn < 4; ++fn) {
      int n = bn + wn + fn * 16 + l15;
      if (n >= Nvalid) continue;
      float bv = bias ? bias[n] : 0.f;
#pragma unroll
      for (int e = 0; e < 4; ++e) {
        int m = bm + wm + fm * 16 + kg * 4 + e;
        int orow = permute_tb ? ((m & 127) * TT + (m >> 7)) : m;
        C[(size_t)orow * ldc + n] = acc[fm][fn][e] + bv;
      }
    }
  }
}

// ============================================================================
// Fused persistent kernel, 256 blocks (1/CU — 99KB LDS pins occupancy, so all
// blocks are guaranteed co-resident on distinct CUs):
//   blocks [0,72):   round-8 GRU recurrence (exact structure, best validated)
//   blocks [72,256): logits workers — consume hb1_seq slots as the barrier
//                    gen counter publishes them, computing the 52-GFLOP
//                    logits GEMM on otherwise-idle CUs. The trailing logits
//                    dispatch is removed.
// Worker tile (t, nb): needs hb1_seq[t+1], written at stage t+1, published
// at barrier idx 2t+3 -> poll grpGen >= 2t+4.
// ============================================================================
struct PArgs {
  const bf16_t *Btru0, *Bt1ru, *Btc0, *Btc1;
  const float  *xg0, *bu, *br, *bc;
  bf16_t *hb0_seq, *hb1_seq, *rh0, *rh1;
  float  *hs0, *hs1, *u0, *u1;
  const bf16_t *Wto;
  const float  *bo;
  float *out;
  unsigned *sync;
};

template<int K>
__device__ __forceinline__ void tile_gemm(
    const bf16_t* __restrict__ A0, const bf16_t* __restrict__ A1,
    const bf16_t* Bs, int wave, int lane, f32x4 (&acc)[2][4])
{
  constexpr int NF = (K == 512) ? 4 : 2;
  const int l15 = lane & 15, kg = lane >> 4;
  const int mw = wave * 32;
#pragma unroll
  for (int i = 0; i < 2; ++i)
#pragma unroll
    for (int f = 0; f < 4; ++f)
#pragma unroll
      for (int e = 0; e < 4; ++e) acc[i][f][e] = 0.f;

#pragma unroll
  for (int kk = 0; kk < K; kk += 32) {
    const bf16_t* Asrc = (kk < 512) ? A0 : A1;
    const int kc = (kk < 512 ? kk : kk - 512) + kg * 8;
    bf16x8 a[2];
#pragma unroll
    for (int i = 0; i < 2; ++i)
      a[i] = cload_bf8(Asrc + (size_t)(mw + i * 16 + l15) * 512 + kc);
    bf16x8 b[NF];
#pragma unroll
    for (int f = 0; f < NF; ++f) {
      int row = f * 16 + l15;
      int byteoff = row * (2 * K) + ((2 * kk + 16 * kg) ^ ((row & 7) << 4));
      b[f] = *(const bf16x8*)((const char*)Bs + byteoff);
    }
#pragma unroll
    for (int i = 0; i < 2; ++i)
#pragma unroll
      for (int f = 0; f < NF; ++f)
        acc[i][f] = __builtin_amdgcn_mfma_f32_16x16x32_bf16(a[i], b[f], acc[i][f], 0, 0, 0);
  }
}

// Stage acc fragments into LDS scratch: accs[col][ROWP] (col-major, padded).
template<int NF>
__device__ __forceinline__ void stage_acc(float* accs, f32x4 (&acc)[2][4],
                                          int wave, int lane)
{
  const int l15 = lane & 15, kg = lane >> 4;
  const int mw = wave * 32;
#pragma unroll
  for (int i = 0; i < 2; ++i)
#pragma unroll
    for (int f = 0; f < NF; ++f)
#pragma unroll
      for (int e = 0; e < 4; ++e)
        accs[(f * 16 + l15) * ROWP + (mw + i * 16 + kg * 4 + e)] = acc[i][f][e];
}

__global__ __launch_bounds__(256) void gru_persist(PArgs P)
{
  const int bid = blockIdx.x, tid = threadIdx.x;
  const int wave = tid >> 6, lane = tid & 63;
  unsigned* sync = P.sync;

  // ===================== logits worker blocks =====================
  if (bid >= NBLK) {
    const int w = bid - NBLK;                 // 0..183
    const int wm = (wave >> 1) * 64, wn = (wave & 1) * 64;
    const int l15 = lane & 15, kg = lane >> 4;
    unsigned* gen = sync + (9 + (w & 7)) * 64;
    for (int tau = w; tau < TT * 79; tau += (NGRID - NBLK)) {
      const int t = tau / 79, nb = tau % 79;
      if (tid == 0) {
        const unsigned need = (unsigned)(2 * t + 4);
        while (__hip_atomic_load(gen, __ATOMIC_RELAXED,
                                 __HIP_MEMORY_SCOPE_AGENT) < need)
          __builtin_amdgcn_s_sleep(32);
      }
      asm volatile("" ::: "memory");
      __syncthreads();
      const bf16_t* A = P.hb1_seq + (size_t)(t + 1) * SLOT;
      const bf16_t* Bp = P.Wto + (size_t)(nb * 128 + wn + l15) * 512 + kg * 8;
      f32x4 acc[4][4];
#pragma unroll
      for (int i = 0; i < 4; ++i)
#pragma unroll
        for (int j = 0; j < 4; ++j)
#pragma unroll
          for (int e = 0; e < 4; ++e) acc[i][j][e] = 0.f;
      for (int kk = 0; kk < 512; kk += 32) {
        bf16x8 a[4], b[4];
#pragma unroll
        for (int i = 0; i < 4; ++i)
          a[i] = cload_bf8(A + (size_t)(wm + i * 16 + l15) * 512 + kk + kg * 8);
#pragma unroll
        for (int j = 0; j < 4; ++j)
          b[j] = *(const bf16x8*)(Bp + (size_t)j * 16 * 512 + kk);
#pragma unroll
        for (int i = 0; i < 4; ++i)
#pragma unroll
          for (int j = 0; j < 4; ++j)
            acc[i][j] = __builtin_amdgcn_mfma_f32_16x16x32_bf16(a[i], b[j], acc[i][j], 0, 0, 0);
      }
#pragma unroll
      for (int fm = 0; fm < 4; ++fm) {
#pragma unroll
        for (int fn = 0; fn < 4; ++fn) {
          int n = nb * 128 + wn + fn * 16 + l15;
          if (n >= VV) continue;
          float bv = P.bo[n];
#pragma unroll
          for (int e = 0; e < 4; ++e) {
            int b_row = wm + fm * 16 + kg * 4 + e;     // batch index
            P.out[(size_t)(b_row * TT + t) * VV + n] = acc[fm][fn][e] + bv;
          }
        }
      }
      __syncthreads();
    }
    return;
  }

  // ===================== persistent recurrence blocks (round-8) ============
  int role, q;
  if (bid < 16)      { role = 0; q = bid; }
  else if (bid < 48) { role = 1; q = bid - 16; }
  else if (bid < 56) { role = 2; q = bid - 48; }
  else               { role = 3; q = bid - 56; }
  const int K  = (role == 0 || role == 2) ? 512 : 1024;
  const int NT = (K == 512) ? 64 : 32;
  const int tileBase = q * NT;

  const bf16_t* Wsrc =
      role == 0 ? P.Btru0 + (size_t)tileBase * 512 :
      role == 1 ? P.Bt1ru + (size_t)tileBase * 1024 :
      role == 2 ? P.Btc0  + (size_t)tileBase * 512 :
                  P.Btc1  + (size_t)tileBase * 1024;

  __shared__ bf16_t Bs[32768];          // 64 KB weight tile (swizzled)
  __shared__ float  accs[64 * ROWP];    // 34 KB epilogue transpose scratch
  {
    const int rsh = (K == 512) ? 10 : 11;
    const int rmask = 2 * K - 1;
#pragma unroll
    for (int it = 0; it < 16; ++it) {
      int ofs = (it * 256 + tid) * 16;
      int row = ofs >> rsh, cb = ofs & rmask;
      *(f4*)((char*)Bs + row * 2 * K + (cb ^ ((row & 7) << 4))) =
          *(const f4*)((const char*)Wsrc + ofs);
    }
  }
  __syncthreads();

  // epilogue mapping constants
  const int c4w = (tid & 15) * 4, r0w = tid >> 4;   // 64-col roles
  const int c4n = (tid & 7) * 4,  r0n = tid >> 3;   // 32-col roles

  for (int s = 0; s <= 40; ++s) {
    // ---------------- phase RU ----------------
    if (role == 0 && s < 40) {
      f32x4 acc[2][4];
      const bf16_t* A0 = P.hb0_seq + (size_t)s * SLOT;
      tile_gemm<512>(A0, A0, Bs, wave, lane, acc);
      stage_acc<4>(accs, acc, wave, lane);
      __syncthreads();
      const float* xg = P.xg0 + (size_t)s * 128 * 1536;
      const bool ublock = (tileBase < 512);
      const int n0 = ublock ? tileBase : tileBase - 512;
#pragma unroll
      for (int p = 0; p < 8; ++p) {
        int row = r0w + p * 16;
        f4 a;
#pragma unroll
        for (int cc = 0; cc < 4; ++cc) a[cc] = accs[(c4w + cc) * ROWP + row];
        f4 xv = *(const f4*)&xg[(size_t)row * 1536 + tileBase + c4w];
        f4 sg;
#pragma unroll
        for (int cc = 0; cc < 4; ++cc) sg[cc] = 1.f / (1.f + expf(-(a[cc] + xv[cc])));
        if (ublock) {
          cstore_f4(&P.u0[row * 512 + n0 + c4w], sg);
        } else {
          f4 h = cload_f4(&P.hs0[row * 512 + n0 + c4w]);
          cst64(&P.rh0[row * 512 + n0 + c4w], pack_bf4(sg * h));
        }
      }
    } else if (role == 1 && s >= 1) {
      f32x4 acc[2][4];
      tile_gemm<1024>(P.hb0_seq + (size_t)s * SLOT,
                      P.hb1_seq + (size_t)(s - 1) * SLOT,
                      Bs, wave, lane, acc);
      stage_acc<2>(accs, acc, wave, lane);
      __syncthreads();
      const bool ublock = (tileBase < 512);
      const int n0 = ublock ? tileBase : tileBase - 512;
      const float* bias = ublock ? (P.bu + 512 + tileBase) : (P.br + tileBase);
#pragma unroll
      for (int p = 0; p < 4; ++p) {
        int row = r0n + p * 32;
        f4 a;
#pragma unroll
        for (int cc = 0; cc < 4; ++cc) a[cc] = accs[(c4n + cc) * ROWP + row];
        f4 bv = *(const f4*)&bias[c4n];
        f4 sg;
#pragma unroll
        for (int cc = 0; cc < 4; ++cc) sg[cc] = 1.f / (1.f + expf(-(a[cc] + bv[cc])));
        if (ublock) {
          cstore_f4(&P.u1[row * 512 + n0 + c4n], sg);
        } else {
          f4 h = cload_f4(&P.hs1[row * 512 + n0 + c4n]);
          cst64(&P.rh1[row * 512 + n0 + c4n], pack_bf4(sg * h));
        }
      }
    }
    gbar(sync, 2 * s);
    // ---------------- phase C ----------------
    if (role == 2 && s < 40) {
      f32x4 acc[2][4];
      tile_gemm<512>(P.rh0, P.rh0, Bs, wave, lane, acc);
      stage_acc<4>(accs, acc, wave, lane);
      __syncthreads();
      const float* xg = P.xg0 + (size_t)s * 128 * 1536;
#pragma unroll
      for (int p = 0; p < 8; ++p) {
        int row = r0w + p * 16;
        int n = tileBase + c4w;
        f4 a;
#pragma unroll
        for (int cc = 0; cc < 4; ++cc) a[cc] = accs[(c4w + cc) * ROWP + row];
        f4 xv = *(const f4*)&xg[(size_t)row * 1536 + 1024 + n];
        f4 cg;
#pragma unroll
        for (int cc = 0; cc < 4; ++cc) cg[cc] = tanhf(a[cc] + xv[cc]);
        f4 u = cload_f4(&P.u0[row * 512 + n]);
        f4 h = cload_f4(&P.hs0[row * 512 + n]);
        f4 hn = u * h + (f4{1.f,1.f,1.f,1.f} - u) * cg;
        cstore_f4(&P.hs0[row * 512 + n], hn);
        cst64(&P.hb0_seq[(size_t)(s + 1) * SLOT + row * 512 + n], pack_bf4(hn));
      }
    } else if (role == 3 && s >= 1) {
      f32x4 acc[2][4];
      tile_gemm<1024>(P.hb0_seq + (size_t)s * SLOT, P.rh1,
                      Bs, wave, lane, acc);
      stage_acc<2>(accs, acc, wave, lane);
      __syncthreads();
#pragma unroll
      for (int p = 0; p < 4; ++p) {
        int row = r0n + p * 32;
        int n = tileBase + c4n;
        f4 a;
#pragma unroll
        for (int cc = 0; cc < 4; ++cc) a[cc] = accs[(c4n + cc) * ROWP + row];
        f4 bv = *(const f4*)&P.bc[512 + n];
        f4 cg;
#pragma unroll
        for (int cc = 0; cc < 4; ++cc) cg[cc] = tanhf(a[cc] + bv[cc]);
        f4 u = cload_f4(&P.u1[row * 512 + n]);
        f4 h = cload_f4(&P.hs1[row * 512 + n]);
        f4 hn = u * h + (f4{1.f,1.f,1.f,1.f} - u) * cg;
        cstore_f4(&P.hs1[row * 512 + n], hn);
        cst64(&P.hb1_seq[(size_t)s * SLOT + row * 512 + n], pack_bf4(hn));
      }
    }
    gbar(sync, 2 * s + 1);
  }
}

// ============================================================================
// h0 = tanh(vgg @ W_in + b_in) via bf16 MFMA, split-K=8.
// ============================================================================
__global__ __launch_bounds__(256) void h0_gemm(
    const bf16_t* __restrict__ vggb, const bf16_t* __restrict__ Wint,
    float* __restrict__ part)
{
  const int bn = blockIdx.x * 128, z = blockIdx.y, k0 = z * 512;
  const int tid = threadIdx.x;
  const int wave = tid >> 6, lane = tid & 63;
  const int wm = (wave >> 1) * 64, wn = (wave & 1) * 64;
  const int l15 = lane & 15, kg = lane >> 4;
  const bf16_t* Ap = vggb + (size_t)(wm + l15) * 4096 + k0 + kg * 8;
  const bf16_t* Bp = Wint + (size_t)(bn + wn + l15) * 4096 + k0 + kg * 8;
  f32x4 acc[4][4];
#pragma unroll
  for (int i = 0; i < 4; ++i)
#pragma unroll
    for (int j = 0; j < 4; ++j)
#pragma unroll
      for (int e = 0; e < 4; ++e) acc[i][j][e] = 0.f;
  for (int kk = 0; kk < 512; kk += 32) {
    bf16x8 a[4], b[4];
#pragma unroll
    for (int i = 0; i < 4; ++i) a[i] = *(const bf16x8*)(Ap + (size_t)i * 16 * 4096 + kk);
#pragma unroll
    for (int j = 0; j < 4; ++j) b[j] = *(const bf16x8*)(Bp + (size_t)j * 16 * 4096 + kk);
#pragma unroll
    for (int i = 0; i < 4; ++i)
#pragma unroll
      for (int j = 0; j < 4; ++j)
        acc[i][j] = __builtin_amdgcn_mfma_f32_16x16x32_bf16(a[i], b[j], acc[i][j], 0, 0, 0);
  }
#pragma unroll
  for (int fm = 0; fm < 4; ++fm)
#pragma unroll
    for (int fn = 0; fn < 4; ++fn) {
      int n = bn + wn + fn * 16 + l15;
#pragma unroll
      for (int e = 0; e < 4; ++e) {
        int m = wm + fm * 16 + kg * 4 + e;
        part[(size_t)z * SLOT + m * 512 + n] = acc[fm][fn][e];
      }
    }
}

__global__ void h0_fin(const float* __restrict__ part, const float* __restrict__ bin,
                       float* __restrict__ hs0, float* __restrict__ hs1,
                       bf16_t* __restrict__ hb00, bf16_t* __restrict__ hb10)
{
  int i = blockIdx.x * 256 + threadIdx.x;   // 65536
  int n = i & 511;
  float s = bin[n];
#pragma unroll
  for (int z = 0; z < 8; ++z) s += part[(size_t)z * SLOT + i];
  float v = tanhf(s);
  hs0[i] = v; hs1[i] = v;
  hb00[i] = (bf16_t)v; hb10[i] = (bf16_t)v;
}

__global__ void conv_bf16(const float* __restrict__ src, bf16_t* __restrict__ dst)
{
  int i = blockIdx.x * 256 + threadIdx.x;
  f4 v = ((const f4*)src)[i];
  dst[i * 4 + 0] = (bf16_t)v[0]; dst[i * 4 + 1] = (bf16_t)v[1];
  dst[i * 4 + 2] = (bf16_t)v[2]; dst[i * 4 + 3] = (bf16_t)v[3];
}

__global__ void gather_emb(const int* __restrict__ tok, const float* __restrict__ emb,
                           bf16_t* __restrict__ A)
{
  int m = blockIdx.x;
  int t = m >> 7, b = m & 127;
  int tk = tok[b * TT + t];
  const float* src = emb + (size_t)tk * 512;
  int i = threadIdx.x;
  f4 v = *(const f4*)(src + i * 4);
  bf16_t* dst = A + (size_t)m * 512 + i * 4;
  dst[0] = (bf16_t)v[0]; dst[1] = (bf16_t)v[1];
  dst[2] = (bf16_t)v[2]; dst[3] = (bf16_t)v[3];
}

struct TJob { const float* src; bf16_t* dst; int K; int dstld; };
struct TJobs10 { TJob j[10]; };
__global__ void transpose_gen(TJobs10 jobs)
{
  TJob jb = jobs.j[blockIdx.z];
  int k0 = blockIdx.x * 32;
  if (k0 >= jb.K) return;
  int n0 = blockIdx.y * 32;
  __shared__ float tile[32][33];
  int tx = threadIdx.x, ty = threadIdx.y;
#pragma unroll
  for (int r = 0; r < 4; ++r)
    tile[ty + 8 * r][tx] = jb.src[(size_t)(k0 + ty + 8 * r) * 512 + n0 + tx];
  __syncthreads();
#pragma unroll
  for (int r = 0; r < 4; ++r)
    jb.dst[(size_t)(n0 + ty + 8 * r) * jb.dstld + k0 + tx] = (bf16_t)tile[tx][ty + 8 * r];
}

__global__ void transpose_wout(const float* __restrict__ W, bf16_t* __restrict__ dst)
{
  __shared__ float tile[32][33];
  int k0 = blockIdx.x * 32, n0 = blockIdx.y * 32;
  int tx = threadIdx.x, ty = threadIdx.y;
#pragma unroll
  for (int r = 0; r < 4; ++r) {
    int n = n0 + tx;
    tile[ty + 8 * r][tx] = (n < VV) ? W[(size_t)(k0 + ty + 8 * r) * VV + n] : 0.f;
  }
  __syncthreads();
#pragma unroll
  for (int r = 0; r < 4; ++r)
    dst[(size_t)(n0 + ty + 8 * r) * 512 + k0 + tx] = (bf16_t)tile[tx][ty + 8 * r];
}

__global__ void build_xbias(const float* __restrict__ bu, const float* __restrict__ br,
                            const float* __restrict__ bc, float* __restrict__ xb)
{
  int i = blockIdx.x * 256 + threadIdx.x;
  if (i < 2 * 1536) {
    int j = i / 1536, qq = i % 1536;
    int g = qq >> 9, n = qq & 511;
    const float* src = (g == 0) ? bu : (g == 1) ? br : bc;
    xb[i] = src[j * 512 + n];
  }
}

__global__ void write_hfinal(const float* __restrict__ hs0_last,
                             const float* __restrict__ hs1_last,
                             float* __restrict__ out)
{
  int i = blockIdx.x * 256 + threadIdx.x;
  out[i] = hs0_last[i];
  out[65536 + i] = hs1_last[i];
}

// ============================================================================
extern "C" void kernel_launch(void* const* d_in, const int* in_sizes, int n_in,
                              void* d_out, int out_size, void* d_ws, size_t ws_size,
                              hipStream_t stream)
{
  const int*   tok = (const int*)  d_in[0];
  const float* vgg = (const float*)d_in[1];
  const float* emb = (const float*)d_in[2];
  const float* Win = (const float*)d_in[3];
  const float* bin = (const float*)d_in[4];
  const float* Wu  = (const float*)d_in[5];
  const float* bu  = (const float*)d_in[6];
  const float* Wr  = (const float*)d_in[7];
  const float* br  = (const float*)d_in[8];
  const float* Wc  = (const float*)d_in[9];
  const float* bc  = (const float*)d_in[10];
  const float* Wo  = (const float*)d_in[11];
  const float* bo  = (const float*)d_in[12];
  float* out = (float*)d_out;

  size_t off = 0;
  auto alloc = [&](size_t bytes) -> void* {
    void* p = (char*)d_ws + off;
    off += (bytes + 255) & ~(size_t)255;
    return p;
  };
  float*  hs0   = (float*) alloc(SLOT * 4);
  float*  hs1   = (float*) alloc(SLOT * 4);
  float*  u0    = (float*) alloc(SLOT * 4);
  float*  u1    = (float*) alloc(SLOT * 4);
  bf16_t* rh0   = (bf16_t*)alloc(SLOT * 2);
  bf16_t* rh1   = (bf16_t*)alloc(SLOT * 2);
  bf16_t* hb0_seq = (bf16_t*)alloc(41 * SLOT * 2);
  bf16_t* hb1_seq = (bf16_t*)alloc(41 * SLOT * 2);
  bf16_t* Aemb  = (bf16_t*)alloc((size_t)TT * BB * 512 * 2);
  float*  xg0   = (float*) alloc((size_t)TT * BB * 1536 * 4);
  bf16_t* Btx0  = (bf16_t*)alloc((size_t)1536 * 512 * 2);
  bf16_t* Btru0 = (bf16_t*)alloc((size_t)1024 * 512 * 2);
  bf16_t* Btc0  = (bf16_t*)alloc((size_t)512 * 512 * 2);
  bf16_t* Bt1ru = (bf16_t*)alloc((size_t)1024 * 1024 * 2);
  bf16_t* Btc1  = (bf16_t*)alloc((size_t)512 * 1024 * 2);
  bf16_t* Wto   = (bf16_t*)alloc((size_t)10112 * 512 * 2);
  bf16_t* Wint  = (bf16_t*)alloc((size_t)512 * 4096 * 2);
  bf16_t* vggb  = (bf16_t*)alloc((size_t)128 * 4096 * 2);
  float*  h0part= (float*) alloc(8 * SLOT * 4);
  float*  xbias = (float*) alloc(2 * 1536 * 4);
  unsigned* syncws = (unsigned*) alloc(8192);
  if (off > ws_size) return;

  TJobs10 tj;
  tj.j[0] = { Wu,                Btx0,                512, 512 };
  tj.j[1] = { Wr,                Btx0 + 262144,       512, 512 };
  tj.j[2] = { Wc,                Btx0 + 524288,       512, 512 };
  tj.j[3] = { Wu + 262144,       Btru0,               512, 512 };
  tj.j[4] = { Wr + 262144,       Btru0 + 262144,      512, 512 };
  tj.j[5] = { Wc + 262144,       Btc0,                512, 512 };
  tj.j[6] = { Wu + 524288,       Bt1ru,               1024, 1024 };
  tj.j[7] = { Wr + 524288,       Bt1ru + 524288,      1024, 1024 };
  tj.j[8] = { Wc + 524288,       Btc1,                1024, 1024 };
  tj.j[9] = { Win,               Wint,                4096, 4096 };
  transpose_gen<<<dim3(128, 16, 10), dim3(32, 8), 0, stream>>>(tj);
  transpose_wout<<<dim3(16, 316), dim3(32, 8), 0, stream>>>(Wo, Wto);
  build_xbias<<<12, 256, 0, stream>>>(bu, br, bc, xbias);
  gather_emb<<<TT * BB, 128, 0, stream>>>(tok, emb, Aemb);
  conv_bf16<<<512, 256, 0, stream>>>(vgg, vggb);
  zero_sync<<<1, 256, 0, stream>>>(syncws);

  h0_gemm<<<dim3(4, 8), 256, 0, stream>>>(vggb, Wint, h0part);
  h0_fin<<<256, 256, 0, stream>>>(h0part, bin, hs0, hs1, hb0_seq, hb1_seq);

  gemm_bt<<<dim3(40, 12), 256, 0, stream>>>(Aemb, Btx0, xbias, xg0, 1536, 1536, 0);

  PArgs pa;
  pa.Btru0 = Btru0; pa.Bt1ru = Bt1ru; pa.Btc0 = Btc0; pa.Btc1 = Btc1;
  pa.xg0 = xg0; pa.bu = bu; pa.br = br; pa.bc = bc;
  pa.hb0_seq = hb0_seq; pa.hb1_seq = hb1_seq;
  pa.rh0 = rh0; pa.rh1 = rh1;
  pa.hs0 = hs0; pa.hs1 = hs1; pa.u0 = u0; pa.u1 = u1;
  pa.Wto = Wto; pa.bo = bo; pa.out = out;
  pa.sync = syncws;
  gru_persist<<<NGRID, 256, 0, stream>>>(pa);

  // logits now produced inside gru_persist by worker blocks.

  write_hfinal<<<256, 256, 0, stream>>>(hs0, hs1, out + (size_t)BB * TT * VV);
}

// Round 12
// 1386.993 us; speedup vs baseline: 2.3851x; 1.2230x over previous
//
#include <hip/hip_runtime.h>
#include <hip/hip_bf16.h>
#include <math.h>

typedef __bf16 bf16_t;
typedef __bf16 bf16x8 __attribute__((ext_vector_type(8)));
typedef float  f32x4 __attribute__((ext_vector_type(4)));
typedef float  f4    __attribute__((ext_vector_type(4)));
typedef float  f2    __attribute__((ext_vector_type(2)));
typedef unsigned short u16x4 __attribute__((ext_vector_type(4)));
typedef unsigned long long u64;

#define HS  512
#define BB  128
#define TT  40
#define VV  10000
#define VGGN 4096
#define SLOT ((size_t)65536)   // 128*512
#define NBLK 72                // persistent recurrence blocks
#define NGRID 256              // total blocks (72 persist + 184 logits workers)
#define GRPS 8                 // barrier groups (persist blocks only)
#define GSZ  9                 // blocks per group
#define ROWP 133               // padded row-dim of LDS acc scratch

// ============================================================================
// Coherent (agent-scope, L2-bypass) accessors — for buffers REWRITTEN within
// the kernel (u*, hs*, rh*): genuine staleness windows recur each stage, so
// these must read/write at the L3 coherence point.
// Write-once slot panels (hb0_seq/hb1_seq) are written with cst64 (L3 made
// current) but READ with plain cached loads: their lines are demand-fetched
// only AFTER the single write (demand-fetch caches, no HW prefetch), and the
// per-block entry __threadfence() kills stale clean lines left by the
// harness's 0xAA ws-poison or prior graph replays (R5's post-timing race).
// ============================================================================
__device__ __forceinline__ u64 cld64(const void* p) {
  return __hip_atomic_load((const u64*)p, __ATOMIC_RELAXED, __HIP_MEMORY_SCOPE_AGENT);
}
__device__ __forceinline__ void cst64(void* p, u64 v) {
  __hip_atomic_store((u64*)p, v, __ATOMIC_RELAXED, __HIP_MEMORY_SCOPE_AGENT);
}
__device__ __forceinline__ f4 cload_f4(const float* p) {
  f2 lo = __builtin_bit_cast(f2, cld64(p));
  f2 hi = __builtin_bit_cast(f2, cld64(p + 2));
  return f4{lo[0], lo[1], hi[0], hi[1]};
}
__device__ __forceinline__ void cstore_f4(float* p, f4 v) {
  f2 lo = {v[0], v[1]}, hi = {v[2], v[3]};
  cst64(p,     __builtin_bit_cast(u64, lo));
  cst64(p + 2, __builtin_bit_cast(u64, hi));
}
__device__ __forceinline__ u64 pack_bf4(f4 v) {
  u16x4 r;
  r[0] = __builtin_bit_cast(unsigned short, (bf16_t)v[0]);
  r[1] = __builtin_bit_cast(unsigned short, (bf16_t)v[1]);
  r[2] = __builtin_bit_cast(unsigned short, (bf16_t)v[2]);
  r[3] = __builtin_bit_cast(unsigned short, (bf16_t)v[3]);
  return __builtin_bit_cast(u64, r);
}
__device__ __forceinline__ bf16x8 cload_bf8(const bf16_t* p) {
  f2 lo = __builtin_bit_cast(f2, cld64(p));
  f2 hi = __builtin_bit_cast(f2, cld64(p + 4));
  f4 t = {lo[0], lo[1], hi[0], hi[1]};
  return __builtin_bit_cast(bf16x8, t);
}

// ============================================================================
// Hierarchical line-padded grid barrier, SYMMETRIC waiting (round-8 protocol,
// validated). Only the 72 persist blocks arrive/wait; workers read grpGen.
// grpCnt[g]@g*64, rootCnt@512, grpGen[g]@(9+g)*64.
// ============================================================================
__device__ __forceinline__ void gbar(unsigned* sync, unsigned idx)
{
  __syncthreads();                 // per-wave vmcnt(0) drain: stores ACKed @L3
  asm volatile("" ::: "memory");
  if (threadIdx.x == 0) {
    const int g = blockIdx.x / GSZ;
    unsigned a = __hip_atomic_fetch_add(&sync[g * 64], 1u,
                                        __ATOMIC_RELAXED, __HIP_MEMORY_SCOPE_AGENT);
    if ((a + 1u) % GSZ == 0u) {
      unsigned r = __hip_atomic_fetch_add(&sync[512], 1u,
                                          __ATOMIC_RELAXED, __HIP_MEMORY_SCOPE_AGENT);
      if ((r + 1u) % GRPS == 0u) {
        unsigned k = (r + 1u) / GRPS;
#pragma unroll
        for (int j = 0; j < GRPS; ++j)
          __hip_atomic_store(&sync[(9 + j) * 64], k,
                             __ATOMIC_RELAXED, __HIP_MEMORY_SCOPE_AGENT);
      }
    }
    while (__hip_atomic_load(&sync[(9 + g) * 64],
                             __ATOMIC_RELAXED, __HIP_MEMORY_SCOPE_AGENT) <= idx)
      __builtin_amdgcn_s_sleep(8);
  }
  asm volatile("" ::: "memory");
  __syncthreads();
}

__global__ void zero_sync(unsigned* p)
{
  for (int i = threadIdx.x; i < 2048; i += 256) p[i] = 0u;
}

// ============================================================================
// Batched MFMA GEMM: C[M,N] = A[M,512] @ Bt[N,512]^T (+bias), fp32 out.
// (used for the xg0 pass)
// ============================================================================
__global__ __launch_bounds__(256) void gemm_bt(
    const bf16_t* __restrict__ A, const bf16_t* __restrict__ Bt,
    const float* __restrict__ bias, float* __restrict__ C,
    int Nvalid, int ldc, int permute_tb)
{
  const int bm = blockIdx.x * 128, bn = blockIdx.y * 128;
  const int tid = threadIdx.x;
  const int wave = tid >> 6, lane = tid & 63;
  const int wm = (wave >> 1) * 64, wn = (wave & 1) * 64;
  const int l15 = lane & 15, kg = lane >> 4;
  const bf16_t* Ap = A + (size_t)(bm + wm + l15) * 512 + kg * 8;
  const bf16_t* Bp = Bt + (size_t)(bn + wn + l15) * 512 + kg * 8;
  f32x4 acc[4][4];
#pragma unroll
  for (int i = 0; i < 4; ++i)
#pragma unroll
    for (int j = 0; j < 4; ++j)
#pragma unroll
      for (int e = 0; e < 4; ++e) acc[i][j][e] = 0.f;

  for (int kk = 0; kk < 512; kk += 32) {
    bf16x8 a[4], b[4];
#pragma unroll
    for (int i = 0; i < 4; ++i) a[i] = *(const bf16x8*)(Ap + (size_t)i * 16 * 512 + kk);
#pragma unroll
    for (int j = 0; j < 4; ++j) b[j] = *(const bf16x8*)(Bp + (size_t)j * 16 * 512 + kk);
#pragma unroll
    for (int i = 0; i < 4; ++i)
#pragma unroll
      for (int j = 0; j < 4; ++j)
        acc[i][j] = __builtin_amdgcn_mfma_f32_16x16x32_bf16(a[i], b[j], acc[i][j], 0, 0, 0);
  }

#pragma unroll
  for (int fm = 0; fm < 4; ++fm) {
#pragma unroll
    for (int fn = 0; fn < 4; ++fn) {
      int n = bn + wn + fn * 16 + l15;
      if (n >= Nvalid) continue;
      float bv = bias ? bias[n] : 0.f;
#pragma unroll
      for (int e = 0; e < 4; ++e) {
        int m = bm + wm + fm * 16 + kg * 4 + e;
        int orow = permute_tb ? ((m & 127) * TT + (m >> 7)) : m;
        C[(size_t)orow * ldc + n] = acc[fm][fn][e] + bv;
      }
    }
  }
}

// ============================================================================
// Fused persistent kernel, 256 blocks (1/CU):
//   blocks [0,72):   round-8 GRU recurrence
//   blocks [72,256): logits workers consuming hb1_seq slots as published
// A-panels (hb slots) now read via PLAIN cached loads (L2-shared across the
// XCD's blocks); in-place buffers stay coherent. Entry __threadfence() per
// block invalidates stale clean L2/L1 lines once per launch.
// ============================================================================
struct PArgs {
  const bf16_t *Btru0, *Bt1ru, *Btc0, *Btc1;
  const float  *xg0, *bu, *br, *bc;
  bf16_t *hb0_seq, *hb1_seq, *rh0, *rh1;
  float  *hs0, *hs1, *u0, *u1;
  const bf16_t *Wto;
  const float  *bo;
  float *out;
  unsigned *sync;
};

// P0/P1: true = plain cached load (write-once slot panel), false = coherent.
template<int K, bool P0, bool P1>
__device__ __forceinline__ void tile_gemm(
    const bf16_t* __restrict__ A0, const bf16_t* __restrict__ A1,
    const bf16_t* Bs, int wave, int lane, f32x4 (&acc)[2][4])
{
  constexpr int NF = (K == 512) ? 4 : 2;
  const int l15 = lane & 15, kg = lane >> 4;
  const int mw = wave * 32;
#pragma unroll
  for (int i = 0; i < 2; ++i)
#pragma unroll
    for (int f = 0; f < 4; ++f)
#pragma unroll
      for (int e = 0; e < 4; ++e) acc[i][f][e] = 0.f;

#pragma unroll
  for (int kk = 0; kk < K; kk += 32) {
    const bf16_t* Asrc = (kk < 512) ? A0 : A1;
    const bool plain = (kk < 512) ? P0 : P1;
    const int kc = (kk < 512 ? kk : kk - 512) + kg * 8;
    bf16x8 a[2];
#pragma unroll
    for (int i = 0; i < 2; ++i) {
      const bf16_t* ap = Asrc + (size_t)(mw + i * 16 + l15) * 512 + kc;
      a[i] = plain ? *(const bf16x8*)ap : cload_bf8(ap);
    }
    bf16x8 b[NF];
#pragma unroll
    for (int f = 0; f < NF; ++f) {
      int row = f * 16 + l15;
      int byteoff = row * (2 * K) + ((2 * kk + 16 * kg) ^ ((row & 7) << 4));
      b[f] = *(const bf16x8*)((const char*)Bs + byteoff);
    }
#pragma unroll
    for (int i = 0; i < 2; ++i)
#pragma unroll
      for (int f = 0; f < NF; ++f)
        acc[i][f] = __builtin_amdgcn_mfma_f32_16x16x32_bf16(a[i], b[f], acc[i][f], 0, 0, 0);
  }
}

// Stage acc fragments into LDS scratch: accs[col][ROWP] (col-major, padded).
template<int NF>
__device__ __forceinline__ void stage_acc(float* accs, f32x4 (&acc)[2][4],
                                          int wave, int lane)
{
  const int l15 = lane & 15, kg = lane >> 4;
  const int mw = wave * 32;
#pragma unroll
  for (int i = 0; i < 2; ++i)
#pragma unroll
    for (int f = 0; f < NF; ++f)
#pragma unroll
      for (int e = 0; e < 4; ++e)
        accs[(f * 16 + l15) * ROWP + (mw + i * 16 + kg * 4 + e)] = acc[i][f][e];
}

__global__ __launch_bounds__(256) void gru_persist(PArgs P)
{
  const int bid = blockIdx.x, tid = threadIdx.x;
  const int wave = tid >> 6, lane = tid & 63;
  unsigned* sync = P.sync;

  // One-time per-block L2/L1 invalidate: kills stale CLEAN lines seeded by
  // the harness's 0xAA ws-poison or previous graph replays, before any plain
  // cached read of kernel-written slot panels. Cost ~once per launch.
  __threadfence();
  __syncthreads();

  // ===================== logits worker blocks =====================
  if (bid >= NBLK) {
    const int w = bid - NBLK;                 // 0..183
    const int wm = (wave >> 1) * 64, wn = (wave & 1) * 64;
    const int l15 = lane & 15, kg = lane >> 4;
    unsigned* gen = sync + (9 + (w & 7)) * 64;
    for (int tau = w; tau < TT * 79; tau += (NGRID - NBLK)) {
      const int t = tau / 79, nb = tau % 79;
      if (tid == 0) {
        const unsigned need = (unsigned)(2 * t + 4);
        while (__hip_atomic_load(gen, __ATOMIC_RELAXED,
                                 __HIP_MEMORY_SCOPE_AGENT) < need)
          __builtin_amdgcn_s_sleep(32);
      }
      asm volatile("" ::: "memory");
      __syncthreads();
      const bf16_t* A = P.hb1_seq + (size_t)(t + 1) * SLOT;
      const bf16_t* Bp = P.Wto + (size_t)(nb * 128 + wn + l15) * 512 + kg * 8;
      f32x4 acc[4][4];
#pragma unroll
      for (int i = 0; i < 4; ++i)
#pragma unroll
        for (int j = 0; j < 4; ++j)
#pragma unroll
          for (int e = 0; e < 4; ++e) acc[i][j][e] = 0.f;
      for (int kk = 0; kk < 512; kk += 32) {
        bf16x8 a[4], b[4];
#pragma unroll
        for (int i = 0; i < 4; ++i)
          a[i] = *(const bf16x8*)(A + (size_t)(wm + i * 16 + l15) * 512 + kk + kg * 8);
#pragma unroll
        for (int j = 0; j < 4; ++j)
          b[j] = *(const bf16x8*)(Bp + (size_t)j * 16 * 512 + kk);
#pragma unroll
        for (int i = 0; i < 4; ++i)
#pragma unroll
          for (int j = 0; j < 4; ++j)
            acc[i][j] = __builtin_amdgcn_mfma_f32_16x16x32_bf16(a[i], b[j], acc[i][j], 0, 0, 0);
      }
#pragma unroll
      for (int fm = 0; fm < 4; ++fm) {
#pragma unroll
        for (int fn = 0; fn < 4; ++fn) {
          int n = nb * 128 + wn + fn * 16 + l15;
          if (n >= VV) continue;
          float bv = P.bo[n];
#pragma unroll
          for (int e = 0; e < 4; ++e) {
            int b_row = wm + fm * 16 + kg * 4 + e;     // batch index
            P.out[(size_t)(b_row * TT + t) * VV + n] = acc[fm][fn][e] + bv;
          }
        }
      }
      __syncthreads();
    }
    return;
  }

  // ===================== persistent recurrence blocks (round-8) ============
  int role, q;
  if (bid < 16)      { role = 0; q = bid; }
  else if (bid < 48) { role = 1; q = bid - 16; }
  else if (bid < 56) { role = 2; q = bid - 48; }
  else               { role = 3; q = bid - 56; }
  const int K  = (role == 0 || role == 2) ? 512 : 1024;
  const int NT = (K == 512) ? 64 : 32;
  const int tileBase = q * NT;

  const bf16_t* Wsrc =
      role == 0 ? P.Btru0 + (size_t)tileBase * 512 :
      role == 1 ? P.Bt1ru + (size_t)tileBase * 1024 :
      role == 2 ? P.Btc0  + (size_t)tileBase * 512 :
                  P.Btc1  + (size_t)tileBase * 1024;

  __shared__ bf16_t Bs[32768];          // 64 KB weight tile (swizzled)
  __shared__ float  accs[64 * ROWP];    // 34 KB epilogue transpose scratch
  {
    const int rsh = (K == 512) ? 10 : 11;
    const int rmask = 2 * K - 1;
#pragma unroll
    for (int it = 0; it < 16; ++it) {
      int ofs = (it * 256 + tid) * 16;
      int row = ofs >> rsh, cb = ofs & rmask;
      *(f4*)((char*)Bs + row * 2 * K + (cb ^ ((row & 7) << 4))) =
          *(const f4*)((const char*)Wsrc + ofs);
    }
  }
  __syncthreads();

  // epilogue mapping constants
  const int c4w = (tid & 15) * 4, r0w = tid >> 4;   // 64-col roles
  const int c4n = (tid & 7) * 4,  r0n = tid >> 3;   // 32-col roles

  for (int s = 0; s <= 40; ++s) {
    // ---------------- phase RU ----------------
    if (role == 0 && s < 40) {
      f32x4 acc[2][4];
      const bf16_t* A0 = P.hb0_seq + (size_t)s * SLOT;
      tile_gemm<512, true, true>(A0, A0, Bs, wave, lane, acc);
      stage_acc<4>(accs, acc, wave, lane);
      __syncthreads();
      const float* xg = P.xg0 + (size_t)s * 128 * 1536;
      const bool ublock = (tileBase < 512);
      const int n0 = ublock ? tileBase : tileBase - 512;
#pragma unroll
      for (int p = 0; p < 8; ++p) {
        int row = r0w + p * 16;
        f4 a;
#pragma unroll
        for (int cc = 0; cc < 4; ++cc) a[cc] = accs[(c4w + cc) * ROWP + row];
        f4 xv = *(const f4*)&xg[(size_t)row * 1536 + tileBase + c4w];
        f4 sg;
#pragma unroll
        for (int cc = 0; cc < 4; ++cc) sg[cc] = 1.f / (1.f + expf(-(a[cc] + xv[cc])));
        if (ublock) {
          cstore_f4(&P.u0[row * 512 + n0 + c4w], sg);
        } else {
          f4 h = cload_f4(&P.hs0[row * 512 + n0 + c4w]);
          cst64(&P.rh0[row * 512 + n0 + c4w], pack_bf4(sg * h));
        }
      }
    } else if (role == 1 && s >= 1) {
      f32x4 acc[2][4];
      tile_gemm<1024, true, true>(P.hb0_seq + (size_t)s * SLOT,
                                  P.hb1_seq + (size_t)(s - 1) * SLOT,
                                  Bs, wave, lane, acc);
      stage_acc<2>(accs, acc, wave, lane);
      __syncthreads();
      const bool ublock = (tileBase < 512);
      const int n0 = ublock ? tileBase : tileBase - 512;
      const float* bias = ublock ? (P.bu + 512 + tileBase) : (P.br + tileBase);
#pragma unroll
      for (int p = 0; p < 4; ++p) {
        int row = r0n + p * 32;
        f4 a;
#pragma unroll
        for (int cc = 0; cc < 4; ++cc) a[cc] = accs[(c4n + cc) * ROWP + row];
        f4 bv = *(const f4*)&bias[c4n];
        f4 sg;
#pragma unroll
        for (int cc = 0; cc < 4; ++cc) sg[cc] = 1.f / (1.f + expf(-(a[cc] + bv[cc])));
        if (ublock) {
          cstore_f4(&P.u1[row * 512 + n0 + c4n], sg);
        } else {
          f4 h = cload_f4(&P.hs1[row * 512 + n0 + c4n]);
          cst64(&P.rh1[row * 512 + n0 + c4n], pack_bf4(sg * h));
        }
      }
    }
    gbar(sync, 2 * s);
    // ---------------- phase C ----------------
    if (role == 2 && s < 40) {
      f32x4 acc[2][4];
      tile_gemm<512, false, false>(P.rh0, P.rh0, Bs, wave, lane, acc);
      stage_acc<4>(accs, acc, wave, lane);
      __syncthreads();
      const float* xg = P.xg0 + (size_t)s * 128 * 1536;
#pragma unroll
      for (int p = 0; p < 8; ++p) {
        int row = r0w + p * 16;
        int n = tileBase + c4w;
        f4 a;
#pragma unroll
        for (int cc = 0; cc < 4; ++cc) a[cc] = accs[(c4w + cc) * ROWP + row];
        f4 xv = *(const f4*)&xg[(size_t)row * 1536 + 1024 + n];
        f4 cg;
#pragma unroll
        for (int cc = 0; cc < 4; ++cc) cg[cc] = tanhf(a[cc] + xv[cc]);
        f4 u = cload_f4(&P.u0[row * 512 + n]);
        f4 h = cload_f4(&P.hs0[row * 512 + n]);
        f4 hn = u * h + (f4{1.f,1.f,1.f,1.f} - u) * cg;
        cstore_f4(&P.hs0[row * 512 + n], hn);
        cst64(&P.hb0_seq[(size_t)(s + 1) * SLOT + row * 512 + n], pack_bf4(hn));
      }
    } else if (role == 3 && s >= 1) {
      f32x4 acc[2][4];
      tile_gemm<1024, true, false>(P.hb0_seq + (size_t)s * SLOT, P.rh1,
                                   Bs, wave, lane, acc);
      stage_acc<2>(accs, acc, wave, lane);
      __syncthreads();
#pragma unroll
      for (int p = 0; p < 4; ++p) {
        int row = r0n + p * 32;
        int n = tileBase + c4n;
        f4 a;
#pragma unroll
        for (int cc = 0; cc < 4; ++cc) a[cc] = accs[(c4n + cc) * ROWP + row];
        f4 bv = *(const f4*)&P.bc[512 + n];
        f4 cg;
#pragma unroll
        for (int cc = 0; cc < 4; ++cc) cg[cc] = tanhf(a[cc] + bv[cc]);
        f4 u = cload_f4(&P.u1[row * 512 + n]);
        f4 h = cload_f4(&P.hs1[row * 512 + n]);
        f4 hn = u * h + (f4{1.f,1.f,1.f,1.f} - u) * cg;
        cstore_f4(&P.hs1[row * 512 + n], hn);
        cst64(&P.hb1_seq[(size_t)s * SLOT + row * 512 + n], pack_bf4(hn));
      }
    }
    gbar(sync, 2 * s + 1);
  }
}

// ============================================================================
// h0 = tanh(vgg @ W_in + b_in) via bf16 MFMA, split-K=8.
// ============================================================================
__global__ __launch_bounds__(256) void h0_gemm(
    const bf16_t* __restrict__ vggb, const bf16_t* __restrict__ Wint,
    float* __restrict__ part)
{
  const int bn = blockIdx.x * 128, z = blockIdx.y, k0 = z * 512;
  const int tid = threadIdx.x;
  const int wave = tid >> 6, lane = tid & 63;
  const int wm = (wave >> 1) * 64, wn = (wave & 1) * 64;
  const int l15 = lane & 15, kg = lane >> 4;
  const bf16_t* Ap = vggb + (size_t)(wm + l15) * 4096 + k0 + kg * 8;
  const bf16_t* Bp = Wint + (size_t)(bn + wn + l15) * 4096 + k0 + kg * 8;
  f32x4 acc[4][4];
#pragma unroll
  for (int i = 0; i < 4; ++i)
#pragma unroll
    for (int j = 0; j < 4; ++j)
#pragma unroll
      for (int e = 0; e < 4; ++e) acc[i][j][e] = 0.f;
  for (int kk = 0; kk < 512; kk += 32) {
    bf16x8 a[4], b[4];
#pragma unroll
    for (int i = 0; i < 4; ++i) a[i] = *(const bf16x8*)(Ap + (size_t)i * 16 * 4096 + kk);
#pragma unroll
    for (int j = 0; j < 4; ++j) b[j] = *(const bf16x8*)(Bp + (size_t)j * 16 * 4096 + kk);
#pragma unroll
    for (int i = 0; i < 4; ++i)
#pragma unroll
      for (int j = 0; j < 4; ++j)
        acc[i][j] = __builtin_amdgcn_mfma_f32_16x16x32_bf16(a[i], b[j], acc[i][j], 0, 0, 0);
  }
#pragma unroll
  for (int fm = 0; fm < 4; ++fm)
#pragma unroll
    for (int fn = 0; fn < 4; ++fn) {
      int n = bn + wn + fn * 16 + l15;
#pragma unroll
      for (int e = 0; e < 4; ++e) {
        int m = wm + fm * 16 + kg * 4 + e;
        part[(size_t)z * SLOT + m * 512 + n] = acc[fm][fn][e];
      }
    }
}

__global__ void h0_fin(const float* __restrict__ part, const float* __restrict__ bin,
                       float* __restrict__ hs0, float* __restrict__ hs1,
                       bf16_t* __restrict__ hb00, bf16_t* __restrict__ hb10)
{
  int i = blockIdx.x * 256 + threadIdx.x;   // 65536
  int n = i & 511;
  float s = bin[n];
#pragma unroll
  for (int z = 0; z < 8; ++z) s += part[(size_t)z * SLOT + i];
  float v = tanhf(s);
  hs0[i] = v; hs1[i] = v;
  hb00[i] = (bf16_t)v; hb10[i] = (bf16_t)v;
}

__global__ void conv_bf16(const float* __restrict__ src, bf16_t* __restrict__ dst)
{
  int i = blockIdx.x * 256 + threadIdx.x;
  f4 v = ((const f4*)src)[i];
  dst[i * 4 + 0] = (bf16_t)v[0]; dst[i * 4 + 1] = (bf16_t)v[1];
  dst[i * 4 + 2] = (bf16_t)v[2]; dst[i * 4 + 3] = (bf16_t)v[3];
}

__global__ void gather_emb(const int* __restrict__ tok, const float* __restrict__ emb,
                           bf16_t* __restrict__ A)
{
  int m = blockIdx.x;
  int t = m >> 7, b = m & 127;
  int tk = tok[b * TT + t];
  const float* src = emb + (size_t)tk * 512;
  int i = threadIdx.x;
  f4 v = *(const f4*)(src + i * 4);
  bf16_t* dst = A + (size_t)m * 512 + i * 4;
  dst[0] = (bf16_t)v[0]; dst[1] = (bf16_t)v[1];
  dst[2] = (bf16_t)v[2]; dst[3] = (bf16_t)v[3];
}

struct TJob { const float* src; bf16_t* dst; int K; int dstld; };
struct TJobs10 { TJob j[10]; };
__global__ void transpose_gen(TJobs10 jobs)
{
  TJob jb = jobs.j[blockIdx.z];
  int k0 = blockIdx.x * 32;
  if (k0 >= jb.K) return;
  int n0 = blockIdx.y * 32;
  __shared__ float tile[32][33];
  int tx = threadIdx.x, ty = threadIdx.y;
#pragma unroll
  for (int r = 0; r < 4; ++r)
    tile[ty + 8 * r][tx] = jb.src[(size_t)(k0 + ty + 8 * r) * 512 + n0 + tx];
  __syncthreads();
#pragma unroll
  for (int r = 0; r < 4; ++r)
    jb.dst[(size_t)(n0 + ty + 8 * r) * jb.dstld + k0 + tx] = (bf16_t)tile[tx][ty + 8 * r];
}

__global__ void transpose_wout(const float* __restrict__ W, bf16_t* __restrict__ dst)
{
  __shared__ float tile[32][33];
  int k0 = blockIdx.x * 32, n0 = blockIdx.y * 32;
  int tx = threadIdx.x, ty = threadIdx.y;
#pragma unroll
  for (int r = 0; r < 4; ++r) {
    int n = n0 + tx;
    tile[ty + 8 * r][tx] = (n < VV) ? W[(size_t)(k0 + ty + 8 * r) * VV + n] : 0.f;
  }
  __syncthreads();
#pragma unroll
  for (int r = 0; r < 4; ++r)
    dst[(size_t)(n0 + ty + 8 * r) * 512 + k0 + tx] = (bf16_t)tile[tx][ty + 8 * r];
}

__global__ void build_xbias(const float* __restrict__ bu, const float* __restrict__ br,
                            const float* __restrict__ bc, float* __restrict__ xb)
{
  int i = blockIdx.x * 256 + threadIdx.x;
  if (i < 2 * 1536) {
    int j = i / 1536, qq = i % 1536;
    int g = qq >> 9, n = qq & 511;
    const float* src = (g == 0) ? bu : (g == 1) ? br : bc;
    xb[i] = src[j * 512 + n];
  }
}

__global__ void write_hfinal(const float* __restrict__ hs0_last,
                             const float* __restrict__ hs1_last,
                             float* __restrict__ out)
{
  int i = blockIdx.x * 256 + threadIdx.x;
  out[i] = hs0_last[i];
  out[65536 + i] = hs1_last[i];
}

// ============================================================================
extern "C" void kernel_launch(void* const* d_in, const int* in_sizes, int n_in,
                              void* d_out, int out_size, void* d_ws, size_t ws_size,
                              hipStream_t stream)
{
  const int*   tok = (const int*)  d_in[0];
  const float* vgg = (const float*)d_in[1];
  const float* emb = (const float*)d_in[2];
  const float* Win = (const float*)d_in[3];
  const float* bin = (const float*)d_in[4];
  const float* Wu  = (const float*)d_in[5];
  const float* bu  = (const float*)d_in[6];
  const float* Wr  = (const float*)d_in[7];
  const float* br  = (const float*)d_in[8];
  const float* Wc  = (const float*)d_in[9];
  const float* bc  = (const float*)d_in[10];
  const float* Wo  = (const float*)d_in[11];
  const float* bo  = (const float*)d_in[12];
  float* out = (float*)d_out;

  size_t off = 0;
  auto alloc = [&](size_t bytes) -> void* {
    void* p = (char*)d_ws + off;
    off += (bytes + 255) & ~(size_t)255;
    return p;
  };
  float*  hs0   = (float*) alloc(SLOT * 4);
  float*  hs1   = (float*) alloc(SLOT * 4);
  float*  u0    = (float*) alloc(SLOT * 4);
  float*  u1    = (float*) alloc(SLOT * 4);
  bf16_t* rh0   = (bf16_t*)alloc(SLOT * 2);
  bf16_t* rh1   = (bf16_t*)alloc(SLOT * 2);
  bf16_t* hb0_seq = (bf16_t*)alloc(41 * SLOT * 2);
  bf16_t* hb1_seq = (bf16_t*)alloc(41 * SLOT * 2);
  bf16_t* Aemb  = (bf16_t*)alloc((size_t)TT * BB * 512 * 2);
  float*  xg0   = (float*) alloc((size_t)TT * BB * 1536 * 4);
  bf16_t* Btx0  = (bf16_t*)alloc((size_t)1536 * 512 * 2);
  bf16_t* Btru0 = (bf16_t*)alloc((size_t)1024 * 512 * 2);
  bf16_t* Btc0  = (bf16_t*)alloc((size_t)512 * 512 * 2);
  bf16_t* Bt1ru = (bf16_t*)alloc((size_t)1024 * 1024 * 2);
  bf16_t* Btc1  = (bf16_t*)alloc((size_t)512 * 1024 * 2);
  bf16_t* Wto   = (bf16_t*)alloc((size_t)10112 * 512 * 2);
  bf16_t* Wint  = (bf16_t*)alloc((size_t)512 * 4096 * 2);
  bf16_t* vggb  = (bf16_t*)alloc((size_t)128 * 4096 * 2);
  float*  h0part= (float*) alloc(8 * SLOT * 4);
  float*  xbias = (float*) alloc(2 * 1536 * 4);
  unsigned* syncws = (unsigned*) alloc(8192);
  if (off > ws_size) return;

  TJobs10 tj;
  tj.j[0] = { Wu,                Btx0,                512, 512 };
  tj.j[1] = { Wr,                Btx0 + 262144,       512, 512 };
  tj.j[2] = { Wc,                Btx0 + 524288,       512, 512 };
  tj.j[3] = { Wu + 262144,       Btru0,               512, 512 };
  tj.j[4] = { Wr + 262144,       Btru0 + 262144,      512, 512 };
  tj.j[5] = { Wc + 262144,       Btc0,                512, 512 };
  tj.j[6] = { Wu + 524288,       Bt1ru,               1024, 1024 };
  tj.j[7] = { Wr + 524288,       Bt1ru + 524288,      1024, 1024 };
  tj.j[8] = { Wc + 524288,       Btc1,                1024, 1024 };
  tj.j[9] = { Win,               Wint,                4096, 4096 };
  transpose_gen<<<dim3(128, 16, 10), dim3(32, 8), 0, stream>>>(tj);
  transpose_wout<<<dim3(16, 316), dim3(32, 8), 0, stream>>>(Wo, Wto);
  build_xbias<<<12, 256, 0, stream>>>(bu, br, bc, xbias);
  gather_emb<<<TT * BB, 128, 0, stream>>>(tok, emb, Aemb);
  conv_bf16<<<512, 256, 0, stream>>>(vgg, vggb);
  zero_sync<<<1, 256, 0, stream>>>(syncws);

  h0_gemm<<<dim3(4, 8), 256, 0, stream>>>(vggb, Wint, h0part);
  h0_fin<<<256, 256, 0, stream>>>(h0part, bin, hs0, hs1, hb0_seq, hb1_seq);

  gemm_bt<<<dim3(40, 12), 256, 0, stream>>>(Aemb, Btx0, xbias, xg0, 1536, 1536, 0);

  PArgs pa;
  pa.Btru0 = Btru0; pa.Bt1ru = Bt1ru; pa.Btc0 = Btc0; pa.Btc1 = Btc1;
  pa.xg0 = xg0; pa.bu = bu; pa.br = br; pa.bc = bc;
  pa.hb0_seq = hb0_seq; pa.hb1_seq = hb1_seq;
  pa.rh0 = rh0; pa.rh1 = rh1;
  pa.hs0 = hs0; pa.hs1 = hs1; pa.u0 = u0; pa.u1 = u1;
  pa.Wto = Wto; pa.bo = bo; pa.out = out;
  pa.sync = syncws;
  gru_persist<<<NGRID, 256, 0, stream>>>(pa);

  // logits produced inside gru_persist by worker blocks.

  write_hfinal<<<256, 256, 0, stream>>>(hs0, hs1, out + (size_t)BB * TT * VV);
}

// Round 13
// 1351.772 us; speedup vs baseline: 2.4472x; 1.0261x over previous
//
#include <hip/hip_runtime.h>
#include <hip/hip_bf16.h>
#include <math.h>

typedef __bf16 bf16_t;
typedef __bf16 bf16x8 __attribute__((ext_vector_type(8)));
typedef float  f32x4 __attribute__((ext_vector_type(4)));
typedef float  f4    __attribute__((ext_vector_type(4)));
typedef float  f2    __attribute__((ext_vector_type(2)));
typedef unsigned short u16x4 __attribute__((ext_vector_type(4)));
typedef unsigned long long u64;

#define HS  512
#define BB  128
#define TT  40
#define VV  10000
#define VGGN 4096
#define SLOT ((size_t)65536)   // 128*512
#define NBLK 72                // persistent recurrence blocks
#define NGRID 256              // total blocks (72 persist + 184 logits workers)
#define GRPS 8                 // barrier groups (persist blocks only)
#define GSZ  9                 // blocks per group
#define ROWP 133               // padded row-dim of LDS acc scratch

// ============================================================================
// Data-plane protocol (validated R12): every shared buffer is WRITE-ONCE per
// launch (slotted by stage). Producers write with agent-scope (L2-bypass)
// stores so L3 is current; consumers read with PLAIN cached loads — safe
// because (a) reads happen only after the publishing barrier, (b) lines are
// demand-fetched (no HW prefetch), and (c) the per-block entry __threadfence
// invalidates stale clean lines from the harness's 0xAA poison / prior graph
// replays. Only the barrier words remain coherent read+write.
// ============================================================================
__device__ __forceinline__ void cst64(void* p, u64 v) {
  __hip_atomic_store((u64*)p, v, __ATOMIC_RELAXED, __HIP_MEMORY_SCOPE_AGENT);
}
__device__ __forceinline__ void cstore_f4(float* p, f4 v) {
  f2 lo = {v[0], v[1]}, hi = {v[2], v[3]};
  cst64(p,     __builtin_bit_cast(u64, lo));
  cst64(p + 2, __builtin_bit_cast(u64, hi));
}
__device__ __forceinline__ u64 pack_bf4(f4 v) {
  u16x4 r;
  r[0] = __builtin_bit_cast(unsigned short, (bf16_t)v[0]);
  r[1] = __builtin_bit_cast(unsigned short, (bf16_t)v[1]);
  r[2] = __builtin_bit_cast(unsigned short, (bf16_t)v[2]);
  r[3] = __builtin_bit_cast(unsigned short, (bf16_t)v[3]);
  return __builtin_bit_cast(u64, r);
}

// ============================================================================
// Hierarchical line-padded grid barrier, SYMMETRIC waiting (round-8 protocol,
// validated). Only the 72 persist blocks arrive/wait; workers read grpGen.
// grpCnt[g]@g*64, rootCnt@512, grpGen[g]@(9+g)*64.
// ============================================================================
__device__ __forceinline__ void gbar(unsigned* sync, unsigned idx)
{
  __syncthreads();                 // per-wave vmcnt(0) drain: stores ACKed @L3
  asm volatile("" ::: "memory");
  if (threadIdx.x == 0) {
    const int g = blockIdx.x / GSZ;
    unsigned a = __hip_atomic_fetch_add(&sync[g * 64], 1u,
                                        __ATOMIC_RELAXED, __HIP_MEMORY_SCOPE_AGENT);
    if ((a + 1u) % GSZ == 0u) {
      unsigned r = __hip_atomic_fetch_add(&sync[512], 1u,
                                          __ATOMIC_RELAXED, __HIP_MEMORY_SCOPE_AGENT);
      if ((r + 1u) % GRPS == 0u) {
        unsigned k = (r + 1u) / GRPS;
#pragma unroll
        for (int j = 0; j < GRPS; ++j)
          __hip_atomic_store(&sync[(9 + j) * 64], k,
                             __ATOMIC_RELAXED, __HIP_MEMORY_SCOPE_AGENT);
      }
    }
    while (__hip_atomic_load(&sync[(9 + g) * 64],
                             __ATOMIC_RELAXED, __HIP_MEMORY_SCOPE_AGENT) <= idx)
      __builtin_amdgcn_s_sleep(8);
  }
  asm volatile("" ::: "memory");
  __syncthreads();
}

__global__ void zero_sync(unsigned* p)
{
  for (int i = threadIdx.x; i < 2048; i += 256) p[i] = 0u;
}

// ============================================================================
// Batched MFMA GEMM: C[M,N] = A[M,512] @ Bt[N,512]^T (+bias), fp32 out.
// (used for the xg0 pass)
// ============================================================================
__global__ __launch_bounds__(256) void gemm_bt(
    const bf16_t* __restrict__ A, const bf16_t* __restrict__ Bt,
    const float* __restrict__ bias, float* __restrict__ C,
    int Nvalid, int ldc, int permute_tb)
{
  const int bm = blockIdx.x * 128, bn = blockIdx.y * 128;
  const int tid = threadIdx.x;
  const int wave = tid >> 6, lane = tid & 63;
  const int wm = (wave >> 1) * 64, wn = (wave & 1) * 64;
  const int l15 = lane & 15, kg = lane >> 4;
  const bf16_t* Ap = A + (size_t)(bm + wm + l15) * 512 + kg * 8;
  const bf16_t* Bp = Bt + (size_t)(bn + wn + l15) * 512 + kg * 8;
  f32x4 acc[4][4];
#pragma unroll
  for (int i = 0; i < 4; ++i)
#pragma unroll
    for (int j = 0; j < 4; ++j)
#pragma unroll
      for (int e = 0; e < 4; ++e) acc[i][j][e] = 0.f;

  for (int kk = 0; kk < 512; kk += 32) {
    bf16x8 a[4], b[4];
#pragma unroll
    for (int i = 0; i < 4; ++i) a[i] = *(const bf16x8*)(Ap + (size_t)i * 16 * 512 + kk);
#pragma unroll
    for (int j = 0; j < 4; ++j) b[j] = *(const bf16x8*)(Bp + (size_t)j * 16 * 512 + kk);
#pragma unroll
    for (int i = 0; i < 4; ++i)
#pragma unroll
      for (int j = 0; j < 4; ++j)
        acc[i][j] = __builtin_amdgcn_mfma_f32_16x16x32_bf16(a[i], b[j], acc[i][j], 0, 0, 0);
  }

#pragma unroll
  for (int fm = 0; fm < 4; ++fm) {
#pragma unroll
    for (int fn = 0; fn < 4; ++fn) {
      int n = bn + wn + fn * 16 + l15;
      if (n >= Nvalid) continue;
      float bv = bias ? bias[n] : 0.f;
#pragma unroll
      for (int e = 0; e < 4; ++e) {
        int m = bm + wm + fm * 16 + kg * 4 + e;
        int orow = permute_tb ? ((m & 127) * TT + (m >> 7)) : m;
        C[(size_t)orow * ldc + n] = acc[fm][fn][e] + bv;
      }
    }
  }
}

// ============================================================================
// Fused persistent kernel, 256 blocks (1/CU):
//   blocks [0,72):   GRU recurrence (R8 roles/stages; all-slotted data plane)
//   blocks [72,256): logits workers consuming hb1_seq slots as published
// ALL main-loop reads are plain cached loads; shared writes are agent cst64.
// ============================================================================
struct PArgs {
  const bf16_t *Btru0, *Bt1ru, *Btc0, *Btc1;
  const float  *xg0, *bu, *br, *bc;
  bf16_t *hb0_seq, *hb1_seq, *rh0s, *rh1s;
  float  *hs0s, *hs1s, *u0s, *u1s;
  const bf16_t *Wto;
  const float  *bo;
  float *out;
  unsigned *sync;
};

template<int K>
__device__ __forceinline__ void tile_gemm(
    const bf16_t* __restrict__ A0, const bf16_t* __restrict__ A1,
    const bf16_t* Bs, int wave, int lane, f32x4 (&acc)[2][4])
{
  constexpr int NF = (K == 512) ? 4 : 2;
  const int l15 = lane & 15, kg = lane >> 4;
  const int mw = wave * 32;
#pragma unroll
  for (int i = 0; i < 2; ++i)
#pragma unroll
    for (int f = 0; f < 4; ++f)
#pragma unroll
      for (int e = 0; e < 4; ++e) acc[i][f][e] = 0.f;

#pragma unroll
  for (int kk = 0; kk < K; kk += 32) {
    const bf16_t* Asrc = (kk < 512) ? A0 : A1;
    const int kc = (kk < 512 ? kk : kk - 512) + kg * 8;
    bf16x8 a[2];
#pragma unroll
    for (int i = 0; i < 2; ++i)
      a[i] = *(const bf16x8*)(Asrc + (size_t)(mw + i * 16 + l15) * 512 + kc);
    bf16x8 b[NF];
#pragma unroll
    for (int f = 0; f < NF; ++f) {
      int row = f * 16 + l15;
      int byteoff = row * (2 * K) + ((2 * kk + 16 * kg) ^ ((row & 7) << 4));
      b[f] = *(const bf16x8*)((const char*)Bs + byteoff);
    }
#pragma unroll
    for (int i = 0; i < 2; ++i)
#pragma unroll
      for (int f = 0; f < NF; ++f)
        acc[i][f] = __builtin_amdgcn_mfma_f32_16x16x32_bf16(a[i], b[f], acc[i][f], 0, 0, 0);
  }
}

// Stage acc fragments into LDS scratch: accs[col][ROWP] (col-major, padded).
template<int NF>
__device__ __forceinline__ void stage_acc(float* accs, f32x4 (&acc)[2][4],
                                          int wave, int lane)
{
  const int l15 = lane & 15, kg = lane >> 4;
  const int mw = wave * 32;
#pragma unroll
  for (int i = 0; i < 2; ++i)
#pragma unroll
    for (int f = 0; f < NF; ++f)
#pragma unroll
      for (int e = 0; e < 4; ++e)
        accs[(f * 16 + l15) * ROWP + (mw + i * 16 + kg * 4 + e)] = acc[i][f][e];
}

__global__ __launch_bounds__(256) void gru_persist(PArgs P)
{
  const int bid = blockIdx.x, tid = threadIdx.x;
  const int wave = tid >> 6, lane = tid & 63;
  unsigned* sync = P.sync;

  // One-time per-block L2/L1 invalidate (kills stale clean lines from the
  // 0xAA ws-poison / prior replays before any plain read of slot data).
  __threadfence();
  __syncthreads();

  // ===================== logits worker blocks =====================
  if (bid >= NBLK) {
    const int w = bid - NBLK;                 // 0..183
    const int wm = (wave >> 1) * 64, wn = (wave & 1) * 64;
    const int l15 = lane & 15, kg = lane >> 4;
    unsigned* gen = sync + (9 + (w & 7)) * 64;
    for (int tau = w; tau < TT * 79; tau += (NGRID - NBLK)) {
      const int t = tau / 79, nb = tau % 79;
      if (tid == 0) {
        const unsigned need = (unsigned)(2 * t + 4);
        while (__hip_atomic_load(gen, __ATOMIC_RELAXED,
                                 __HIP_MEMORY_SCOPE_AGENT) < need)
          __builtin_amdgcn_s_sleep(32);
      }
      asm volatile("" ::: "memory");
      __syncthreads();
      const bf16_t* A = P.hb1_seq + (size_t)(t + 1) * SLOT;
      const bf16_t* Bp = P.Wto + (size_t)(nb * 128 + wn + l15) * 512 + kg * 8;
      f32x4 acc[4][4];
#pragma unroll
      for (int i = 0; i < 4; ++i)
#pragma unroll
        for (int j = 0; j < 4; ++j)
#pragma unroll
          for (int e = 0; e < 4; ++e) acc[i][j][e] = 0.f;
      for (int kk = 0; kk < 512; kk += 32) {
        bf16x8 a[4], b[4];
#pragma unroll
        for (int i = 0; i < 4; ++i)
          a[i] = *(const bf16x8*)(A + (size_t)(wm + i * 16 + l15) * 512 + kk + kg * 8);
#pragma unroll
        for (int j = 0; j < 4; ++j)
          b[j] = *(const bf16x8*)(Bp + (size_t)j * 16 * 512 + kk);
#pragma unroll
        for (int i = 0; i < 4; ++i)
#pragma unroll
          for (int j = 0; j < 4; ++j)
            acc[i][j] = __builtin_amdgcn_mfma_f32_16x16x32_bf16(a[i], b[j], acc[i][j], 0, 0, 0);
      }
#pragma unroll
      for (int fm = 0; fm < 4; ++fm) {
#pragma unroll
        for (int fn = 0; fn < 4; ++fn) {
          int n = nb * 128 + wn + fn * 16 + l15;
          if (n >= VV) continue;
          float bv = P.bo[n];
#pragma unroll
          for (int e = 0; e < 4; ++e) {
            int b_row = wm + fm * 16 + kg * 4 + e;     // batch index
            P.out[(size_t)(b_row * TT + t) * VV + n] = acc[fm][fn][e] + bv;
          }
        }
      }
      __syncthreads();
    }
    return;
  }

  // ===================== persistent recurrence blocks ======================
  int role, q;
  if (bid < 16)      { role = 0; q = bid; }
  else if (bid < 48) { role = 1; q = bid - 16; }
  else if (bid < 56) { role = 2; q = bid - 48; }
  else               { role = 3; q = bid - 56; }
  const int K  = (role == 0 || role == 2) ? 512 : 1024;
  const int NT = (K == 512) ? 64 : 32;
  const int tileBase = q * NT;

  const bf16_t* Wsrc =
      role == 0 ? P.Btru0 + (size_t)tileBase * 512 :
      role == 1 ? P.Bt1ru + (size_t)tileBase * 1024 :
      role == 2 ? P.Btc0  + (size_t)tileBase * 512 :
                  P.Btc1  + (size_t)tileBase * 1024;

  __shared__ bf16_t Bs[32768];          // 64 KB weight tile (swizzled)
  __shared__ float  accs[64 * ROWP];    // 34 KB epilogue transpose scratch
  {
    const int rsh = (K == 512) ? 10 : 11;
    const int rmask = 2 * K - 1;
#pragma unroll
    for (int it = 0; it < 16; ++it) {
      int ofs = (it * 256 + tid) * 16;
      int row = ofs >> rsh, cb = ofs & rmask;
      *(f4*)((char*)Bs + row * 2 * K + (cb ^ ((row & 7) << 4))) =
          *(const f4*)((const char*)Wsrc + ofs);
    }
  }
  __syncthreads();

  // epilogue mapping constants
  const int c4w = (tid & 15) * 4, r0w = tid >> 4;   // 64-col roles
  const int c4n = (tid & 7) * 4,  r0n = tid >> 3;   // 32-col roles

  for (int s = 0; s <= 40; ++s) {
    // ---------------- phase RU ----------------
    if (role == 0 && s < 40) {
      f32x4 acc[2][4];
      const bf16_t* A0 = P.hb0_seq + (size_t)s * SLOT;
      tile_gemm<512>(A0, A0, Bs, wave, lane, acc);
      stage_acc<4>(accs, acc, wave, lane);
      __syncthreads();
      const float* xg = P.xg0 + (size_t)s * 128 * 1536;
      const float* hs = P.hs0s + (size_t)s * SLOT;
      float* us = P.u0s + (size_t)s * SLOT;
      bf16_t* rhs = P.rh0s + (size_t)s * SLOT;
      const bool ublock = (tileBase < 512);
      const int n0 = ublock ? tileBase : tileBase - 512;
#pragma unroll
      for (int p = 0; p < 8; ++p) {
        int row = r0w + p * 16;
        f4 a;
#pragma unroll
        for (int cc = 0; cc < 4; ++cc) a[cc] = accs[(c4w + cc) * ROWP + row];
        f4 xv = *(const f4*)&xg[(size_t)row * 1536 + tileBase + c4w];
        f4 sg;
#pragma unroll
        for (int cc = 0; cc < 4; ++cc) sg[cc] = 1.f / (1.f + expf(-(a[cc] + xv[cc])));
        if (ublock) {
          cstore_f4(&us[row * 512 + n0 + c4w], sg);
        } else {
          f4 h = *(const f4*)&hs[row * 512 + n0 + c4w];
          cst64(&rhs[row * 512 + n0 + c4w], pack_bf4(sg * h));
        }
      }
    } else if (role == 1 && s >= 1) {
      f32x4 acc[2][4];
      tile_gemm<1024>(P.hb0_seq + (size_t)s * SLOT,
                      P.hb1_seq + (size_t)(s - 1) * SLOT,
                      Bs, wave, lane, acc);
      stage_acc<2>(accs, acc, wave, lane);
      __syncthreads();
      const float* hs = P.hs1s + (size_t)(s - 1) * SLOT;
      float* us = P.u1s + (size_t)s * SLOT;
      bf16_t* rhs = P.rh1s + (size_t)s * SLOT;
      const bool ublock = (tileBase < 512);
      const int n0 = ublock ? tileBase : tileBase - 512;
      const float* bias = ublock ? (P.bu + 512 + tileBase) : (P.br + tileBase);
#pragma unroll
      for (int p = 0; p < 4; ++p) {
        int row = r0n + p * 32;
        f4 a;
#pragma unroll
        for (int cc = 0; cc < 4; ++cc) a[cc] = accs[(c4n + cc) * ROWP + row];
        f4 bv = *(const f4*)&bias[c4n];
        f4 sg;
#pragma unroll
        for (int cc = 0; cc < 4; ++cc) sg[cc] = 1.f / (1.f + expf(-(a[cc] + bv[cc])));
        if (ublock) {
          cstore_f4(&us[row * 512 + n0 + c4n], sg);
        } else {
          f4 h = *(const f4*)&hs[row * 512 + n0 + c4n];
          cst64(&rhs[row * 512 + n0 + c4n], pack_bf4(sg * h));
        }
      }
    }
    gbar(sync, 2 * s);
    // ---------------- phase C ----------------
    if (role == 2 && s < 40) {
      f32x4 acc[2][4];
      const bf16_t* rhs = P.rh0s + (size_t)s * SLOT;
      tile_gemm<512>(rhs, rhs, Bs, wave, lane, acc);
      stage_acc<4>(accs, acc, wave, lane);
      __syncthreads();
      const float* xg = P.xg0 + (size_t)s * 128 * 1536;
      const float* us = P.u0s + (size_t)s * SLOT;
      const float* hs = P.hs0s + (size_t)s * SLOT;
      float* hso = P.hs0s + (size_t)(s + 1) * SLOT;
#pragma unroll
      for (int p = 0; p < 8; ++p) {
        int row = r0w + p * 16;
        int n = tileBase + c4w;
        f4 a;
#pragma unroll
        for (int cc = 0; cc < 4; ++cc) a[cc] = accs[(c4w + cc) * ROWP + row];
        f4 xv = *(const f4*)&xg[(size_t)row * 1536 + 1024 + n];
        f4 cg;
#pragma unroll
        for (int cc = 0; cc < 4; ++cc) cg[cc] = tanhf(a[cc] + xv[cc]);
        f4 u = *(const f4*)&us[row * 512 + n];
        f4 h = *(const f4*)&hs[row * 512 + n];
        f4 hn = u * h + (f4{1.f,1.f,1.f,1.f} - u) * cg;
        cstore_f4(&hso[row * 512 + n], hn);
        cst64(&P.hb0_seq[(size_t)(s + 1) * SLOT + row * 512 + n], pack_bf4(hn));
      }
    } else if (role == 3 && s >= 1) {
      f32x4 acc[2][4];
      tile_gemm<1024>(P.hb0_seq + (size_t)s * SLOT,
                      P.rh1s + (size_t)s * SLOT,
                      Bs, wave, lane, acc);
      stage_acc<2>(accs, acc, wave, lane);
      __syncthreads();
      const float* us = P.u1s + (size_t)s * SLOT;
      const float* hs = P.hs1s + (size_t)(s - 1) * SLOT;
      float* hso = P.hs1s + (size_t)s * SLOT;
#pragma unroll
      for (int p = 0; p < 4; ++p) {
        int row = r0n + p * 32;
        int n = tileBase + c4n;
        f4 a;
#pragma unroll
        for (int cc = 0; cc < 4; ++cc) a[cc] = accs[(c4n + cc) * ROWP + row];
        f4 bv = *(const f4*)&P.bc[512 + n];
        f4 cg;
#pragma unroll
        for (int cc = 0; cc < 4; ++cc) cg[cc] = tanhf(a[cc] + bv[cc]);
        f4 u = *(const f4*)&us[row * 512 + n];
        f4 h = *(const f4*)&hs[row * 512 + n];
        f4 hn = u * h + (f4{1.f,1.f,1.f,1.f} - u) * cg;
        cstore_f4(&hso[row * 512 + n], hn);
        cst64(&P.hb1_seq[(size_t)s * SLOT + row * 512 + n], pack_bf4(hn));
      }
    }
    gbar(sync, 2 * s + 1);
  }
}

// ============================================================================
// h0 = tanh(vgg @ W_in + b_in) via bf16 MFMA, split-K=8.
// ============================================================================
__global__ __launch_bounds__(256) void h0_gemm(
    const bf16_t* __restrict__ vggb, const bf16_t* __restrict__ Wint,
    float* __restrict__ part)
{
  const int bn = blockIdx.x * 128, z = blockIdx.y, k0 = z * 512;
  const int tid = threadIdx.x;
  const int wave = tid >> 6, lane = tid & 63;
  const int wm = (wave >> 1) * 64, wn = (wave & 1) * 64;
  const int l15 = lane & 15, kg = lane >> 4;
  const bf16_t* Ap = vggb + (size_t)(wm + l15) * 4096 + k0 + kg * 8;
  const bf16_t* Bp = Wint + (size_t)(bn + wn + l15) * 4096 + k0 + kg * 8;
  f32x4 acc[4][4];
#pragma unroll
  for (int i = 0; i < 4; ++i)
#pragma unroll
    for (int j = 0; j < 4; ++j)
#pragma unroll
      for (int e = 0; e < 4; ++e) acc[i][j][e] = 0.f;
  for (int kk = 0; kk < 512; kk += 32) {
    bf16x8 a[4], b[4];
#pragma unroll
    for (int i = 0; i < 4; ++i) a[i] = *(const bf16x8*)(Ap + (size_t)i * 16 * 4096 + kk);
#pragma unroll
    for (int j = 0; j < 4; ++j) b[j] = *(const bf16x8*)(Bp + (size_t)j * 16 * 4096 + kk);
#pragma unroll
    for (int i = 0; i < 4; ++i)
#pragma unroll
      for (int j = 0; j < 4; ++j)
        acc[i][j] = __builtin_amdgcn_mfma_f32_16x16x32_bf16(a[i], b[j], acc[i][j], 0, 0, 0);
  }
#pragma unroll
  for (int fm = 0; fm < 4; ++fm)
#pragma unroll
    for (int fn = 0; fn < 4; ++fn) {
      int n = bn + wn + fn * 16 + l15;
#pragma unroll
      for (int e = 0; e < 4; ++e) {
        int m = wm + fm * 16 + kg * 4 + e;
        part[(size_t)z * SLOT + m * 512 + n] = acc[fm][fn][e];
      }
    }
}

__global__ void h0_fin(const float* __restrict__ part, const float* __restrict__ bin,
                       float* __restrict__ hs0, float* __restrict__ hs1,
                       bf16_t* __restrict__ hb00, bf16_t* __restrict__ hb10)
{
  int i = blockIdx.x * 256 + threadIdx.x;   // 65536
  int n = i & 511;
  float s = bin[n];
#pragma unroll
  for (int z = 0; z < 8; ++z) s += part[(size_t)z * SLOT + i];
  float v = tanhf(s);
  hs0[i] = v; hs1[i] = v;
  hb00[i] = (bf16_t)v; hb10[i] = (bf16_t)v;
}

__global__ void conv_bf16(const float* __restrict__ src, bf16_t* __restrict__ dst)
{
  int i = blockIdx.x * 256 + threadIdx.x;
  f4 v = ((const f4*)src)[i];
  dst[i * 4 + 0] = (bf16_t)v[0]; dst[i * 4 + 1] = (bf16_t)v[1];
  dst[i * 4 + 2] = (bf16_t)v[2]; dst[i * 4 + 3] = (bf16_t)v[3];
}

__global__ void gather_emb(const int* __restrict__ tok, const float* __restrict__ emb,
                           bf16_t* __restrict__ A)
{
  int m = blockIdx.x;
  int t = m >> 7, b = m & 127;
  int tk = tok[b * TT + t];
  const float* src = emb + (size_t)tk * 512;
  int i = threadIdx.x;
  f4 v = *(const f4*)(src + i * 4);
  bf16_t* dst = A + (size_t)m * 512 + i * 4;
  dst[0] = (bf16_t)v[0]; dst[1] = (bf16_t)v[1];
  dst[2] = (bf16_t)v[2]; dst[3] = (bf16_t)v[3];
}

struct TJob { const float* src; bf16_t* dst; int K; int dstld; };
struct TJobs10 { TJob j[10]; };
__global__ void transpose_gen(TJobs10 jobs)
{
  TJob jb = jobs.j[blockIdx.z];
  int k0 = blockIdx.x * 32;
  if (k0 >= jb.K) return;
  int n0 = blockIdx.y * 32;
  __shared__ float tile[32][33];
  int tx = threadIdx.x, ty = threadIdx.y;
#pragma unroll
  for (int r = 0; r < 4; ++r)
    tile[ty + 8 * r][tx] = jb.src[(size_t)(k0 + ty + 8 * r) * 512 + n0 + tx];
  __syncthreads();
#pragma unroll
  for (int r = 0; r < 4; ++r)
    jb.dst[(size_t)(n0 + ty + 8 * r) * jb.dstld + k0 + tx] = (bf16_t)tile[tx][ty + 8 * r];
}

__global__ void transpose_wout(const float* __restrict__ W, bf16_t* __restrict__ dst)
{
  __shared__ float tile[32][33];
  int k0 = blockIdx.x * 32, n0 = blockIdx.y * 32;
  int tx = threadIdx.x, ty = threadIdx.y;
#pragma unroll
  for (int r = 0; r < 4; ++r) {
    int n = n0 + tx;
    tile[ty + 8 * r][tx] = (n < VV) ? W[(size_t)(k0 + ty + 8 * r) * VV + n] : 0.f;
  }
  __syncthreads();
#pragma unroll
  for (int r = 0; r < 4; ++r)
    dst[(size_t)(n0 + ty + 8 * r) * 512 + k0 + tx] = (bf16_t)tile[tx][ty + 8 * r];
}

__global__ void build_xbias(const float* __restrict__ bu, const float* __restrict__ br,
                            const float* __restrict__ bc, float* __restrict__ xb)
{
  int i = blockIdx.x * 256 + threadIdx.x;
  if (i < 2 * 1536) {
    int j = i / 1536, qq = i % 1536;
    int g = qq >> 9, n = qq & 511;
    const float* src = (g == 0) ? bu : (g == 1) ? br : bc;
    xb[i] = src[j * 512 + n];
  }
}

__global__ void write_hfinal(const float* __restrict__ hs0_last,
                             const float* __restrict__ hs1_last,
                             float* __restrict__ out)
{
  int i = blockIdx.x * 256 + threadIdx.x;
  out[i] = hs0_last[i];
  out[65536 + i] = hs1_last[i];
}

// ============================================================================
extern "C" void kernel_launch(void* const* d_in, const int* in_sizes, int n_in,
                              void* d_out, int out_size, void* d_ws, size_t ws_size,
                              hipStream_t stream)
{
  const int*   tok = (const int*)  d_in[0];
  const float* vgg = (const float*)d_in[1];
  const float* emb = (const float*)d_in[2];
  const float* Win = (const float*)d_in[3];
  const float* bin = (const float*)d_in[4];
  const float* Wu  = (const float*)d_in[5];
  const float* bu  = (const float*)d_in[6];
  const float* Wr  = (const float*)d_in[7];
  const float* br  = (const float*)d_in[8];
  const float* Wc  = (const float*)d_in[9];
  const float* bc  = (const float*)d_in[10];
  const float* Wo  = (const float*)d_in[11];
  const float* bo  = (const float*)d_in[12];
  float* out = (float*)d_out;

  size_t off = 0;
  auto alloc = [&](size_t bytes) -> void* {
    void* p = (char*)d_ws + off;
    off += (bytes + 255) & ~(size_t)255;
    return p;
  };
  // All shared recurrence buffers are write-once SLOTTED by stage.
  float*  hs0s  = (float*) alloc(41 * SLOT * 4);
  float*  hs1s  = (float*) alloc(41 * SLOT * 4);
  float*  u0s   = (float*) alloc(41 * SLOT * 4);
  float*  u1s   = (float*) alloc(41 * SLOT * 4);
  bf16_t* rh0s  = (bf16_t*)alloc(41 * SLOT * 2);
  bf16_t* rh1s  = (bf16_t*)alloc(41 * SLOT * 2);
  bf16_t* hb0_seq = (bf16_t*)alloc(41 * SLOT * 2);
  bf16_t* hb1_seq = (bf16_t*)alloc(41 * SLOT * 2);
  bf16_t* Aemb  = (bf16_t*)alloc((size_t)TT * BB * 512 * 2);
  float*  xg0   = (float*) alloc((size_t)TT * BB * 1536 * 4);
  bf16_t* Btx0  = (bf16_t*)alloc((size_t)1536 * 512 * 2);
  bf16_t* Btru0 = (bf16_t*)alloc((size_t)1024 * 512 * 2);
  bf16_t* Btc0  = (bf16_t*)alloc((size_t)512 * 512 * 2);
  bf16_t* Bt1ru = (bf16_t*)alloc((size_t)1024 * 1024 * 2);
  bf16_t* Btc1  = (bf16_t*)alloc((size_t)512 * 1024 * 2);
  bf16_t* Wto   = (bf16_t*)alloc((size_t)10112 * 512 * 2);
  bf16_t* Wint  = (bf16_t*)alloc((size_t)512 * 4096 * 2);
  bf16_t* vggb  = (bf16_t*)alloc((size_t)128 * 4096 * 2);
  float*  h0part= (float*) alloc(8 * SLOT * 4);
  float*  xbias = (float*) alloc(2 * 1536 * 4);
  unsigned* syncws = (unsigned*) alloc(8192);
  if (off > ws_size) return;   // ws too small -> silent fail (falsifier a)

  TJobs10 tj;
  tj.j[0] = { Wu,                Btx0,                512, 512 };
  tj.j[1] = { Wr,                Btx0 + 262144,       512, 512 };
  tj.j[2] = { Wc,                Btx0 + 524288,       512, 512 };
  tj.j[3] = { Wu + 262144,       Btru0,               512, 512 };
  tj.j[4] = { Wr + 262144,       Btru0 + 262144,      512, 512 };
  tj.j[5] = { Wc + 262144,       Btc0,                512, 512 };
  tj.j[6] = { Wu + 524288,       Bt1ru,               1024, 1024 };
  tj.j[7] = { Wr + 524288,       Bt1ru + 524288,      1024, 1024 };
  tj.j[8] = { Wc + 524288,       Btc1,                1024, 1024 };
  tj.j[9] = { Win,               Wint,                4096, 4096 };
  transpose_gen<<<dim3(128, 16, 10), dim3(32, 8), 0, stream>>>(tj);
  transpose_wout<<<dim3(16, 316), dim3(32, 8), 0, stream>>>(Wo, Wto);
  build_xbias<<<12, 256, 0, stream>>>(bu, br, bc, xbias);
  gather_emb<<<TT * BB, 128, 0, stream>>>(tok, emb, Aemb);
  conv_bf16<<<512, 256, 0, stream>>>(vgg, vggb);
  zero_sync<<<1, 256, 0, stream>>>(syncws);

  h0_gemm<<<dim3(4, 8), 256, 0, stream>>>(vggb, Wint, h0part);
  h0_fin<<<256, 256, 0, stream>>>(h0part, bin, hs0s, hs1s, hb0_seq, hb1_seq);

  gemm_bt<<<dim3(40, 12), 256, 0, stream>>>(Aemb, Btx0, xbias, xg0, 1536, 1536, 0);

  PArgs pa;
  pa.Btru0 = Btru0; pa.Bt1ru = Bt1ru; pa.Btc0 = Btc0; pa.Btc1 = Btc1;
  pa.xg0 = xg0; pa.bu = bu; pa.br = br; pa.bc = bc;
  pa.hb0_seq = hb0_seq; pa.hb1_seq = hb1_seq;
  pa.rh0s = rh0s; pa.rh1s = rh1s;
  pa.hs0s = hs0s; pa.hs1s = hs1s; pa.u0s = u0s; pa.u1s = u1s;
  pa.Wto = Wto; pa.bo = bo; pa.out = out;
  pa.sync = syncws;
  gru_persist<<<NGRID, 256, 0, stream>>>(pa);

  // logits produced inside gru_persist by worker blocks.

  write_hfinal<<<256, 256, 0, stream>>>(hs0s + 40 * SLOT, hs1s + 40 * SLOT,
                                        out + (size_t)BB * TT * VV);
}

// Round 14
// 1056.905 us; speedup vs baseline: 3.1300x; 1.2790x over previous
//
#include <hip/hip_runtime.h>
#include <hip/hip_bf16.h>
#include <math.h>

typedef __bf16 bf16_t;
typedef __bf16 bf16x8 __attribute__((ext_vector_type(8)));
typedef float  f32x4 __attribute__((ext_vector_type(4)));
typedef float  f4    __attribute__((ext_vector_type(4)));
typedef float  f2    __attribute__((ext_vector_type(2)));
typedef unsigned short u16x4 __attribute__((ext_vector_type(4)));
typedef unsigned long long u64;

#define HS  512
#define BB  128
#define TT  40
#define VV  10000
#define VGGN 4096
#define SLOT ((size_t)65536)   // 128*512
#define NBLK 48                // persistent recurrence blocks (16 L0 + 32 L1)
#define NGRID 256              // total blocks (48 persist + 208 logits workers)
#define GRPS 8                 // barrier groups
#define GSZ  6                 // blocks per group (48 = 8*6)

// ============================================================================
// Data-plane protocol (validated R12/R13): cross-block buffers are WRITE-ONCE
// slots; producers use agent-scope (L2-bypass) stores so L3 is current;
// consumers use PLAIN cached loads (demand-fetch after publication barrier;
// entry __threadfence kills stale clean lines from ws-poison/prior replays).
// NEW (this round): u and h state never cross blocks — column-ownership keeps
// them in fragment REGISTERS across phases/steps. Only rh + hb are published.
// ============================================================================
__device__ __forceinline__ void cst64(void* p, u64 v) {
  __hip_atomic_store((u64*)p, v, __ATOMIC_RELAXED, __HIP_MEMORY_SCOPE_AGENT);
}

// ============================================================================
// Hierarchical line-padded grid barrier, SYMMETRIC waiting (R8 protocol).
// 48 blocks = 8 groups x 6. grpCnt[g]@g*64, rootCnt@512, grpGen[g]@(9+g)*64.
// Workers poll grpGen lines read-only.
// ============================================================================
__device__ __forceinline__ void gbar(unsigned* sync, unsigned idx)
{
  __syncthreads();                 // per-wave vmcnt(0) drain: stores ACKed @L3
  asm volatile("" ::: "memory");
  if (threadIdx.x == 0) {
    const int g = blockIdx.x / GSZ;
    unsigned a = __hip_atomic_fetch_add(&sync[g * 64], 1u,
                                        __ATOMIC_RELAXED, __HIP_MEMORY_SCOPE_AGENT);
    if ((a + 1u) % GSZ == 0u) {
      unsigned r = __hip_atomic_fetch_add(&sync[512], 1u,
                                          __ATOMIC_RELAXED, __HIP_MEMORY_SCOPE_AGENT);
      if ((r + 1u) % GRPS == 0u) {
        unsigned k = (r + 1u) / GRPS;
#pragma unroll
        for (int j = 0; j < GRPS; ++j)
          __hip_atomic_store(&sync[(9 + j) * 64], k,
                             __ATOMIC_RELAXED, __HIP_MEMORY_SCOPE_AGENT);
      }
    }
    while (__hip_atomic_load(&sync[(9 + g) * 64],
                             __ATOMIC_RELAXED, __HIP_MEMORY_SCOPE_AGENT) <= idx)
      __builtin_amdgcn_s_sleep(8);
  }
  asm volatile("" ::: "memory");
  __syncthreads();
}

__global__ void zero_sync(unsigned* p)
{
  for (int i = threadIdx.x; i < 2048; i += 256) p[i] = 0u;
}

// ============================================================================
// Batched MFMA GEMM: C[M,N] = A[M,512] @ Bt[N,512]^T (+bias), fp32 out.
// (used for the xg0 pass)
// ============================================================================
__global__ __launch_bounds__(256) void gemm_bt(
    const bf16_t* __restrict__ A, const bf16_t* __restrict__ Bt,
    const float* __restrict__ bias, float* __restrict__ C,
    int Nvalid, int ldc, int permute_tb)
{
  const int bm = blockIdx.x * 128, bn = blockIdx.y * 128;
  const int tid = threadIdx.x;
  const int wave = tid >> 6, lane = tid & 63;
  const int wm = (wave >> 1) * 64, wn = (wave & 1) * 64;
  const int l15 = lane & 15, kg = lane >> 4;
  const bf16_t* Ap = A + (size_t)(bm + wm + l15) * 512 + kg * 8;
  const bf16_t* Bp = Bt + (size_t)(bn + wn + l15) * 512 + kg * 8;
  f32x4 acc[4][4];
#pragma unroll
  for (int i = 0; i < 4; ++i)
#pragma unroll
    for (int j = 0; j < 4; ++j)
#pragma unroll
      for (int e = 0; e < 4; ++e) acc[i][j][e] = 0.f;

  for (int kk = 0; kk < 512; kk += 32) {
    bf16x8 a[4], b[4];
#pragma unroll
    for (int i = 0; i < 4; ++i) a[i] = *(const bf16x8*)(Ap + (size_t)i * 16 * 512 + kk);
#pragma unroll
    for (int j = 0; j < 4; ++j) b[j] = *(const bf16x8*)(Bp + (size_t)j * 16 * 512 + kk);
#pragma unroll
    for (int i = 0; i < 4; ++i)
#pragma unroll
      for (int j = 0; j < 4; ++j)
        acc[i][j] = __builtin_amdgcn_mfma_f32_16x16x32_bf16(a[i], b[j], acc[i][j], 0, 0, 0);
  }

#pragma unroll
  for (int fm = 0; fm < 4; ++fm) {
#pragma unroll
    for (int fn = 0; fn < 4; ++fn) {
      int n = bn + wn + fn * 16 + l15;
      if (n >= Nvalid) continue;
      float bv = bias ? bias[n] : 0.f;
#pragma unroll
      for (int e = 0; e < 4; ++e) {
        int m = bm + wm + fm * 16 + kg * 4 + e;
        int orow = permute_tb ? ((m & 127) * TT + (m >> 7)) : m;
        C[(size_t)orow * ldc + n] = acc[fm][fn][e] + bv;
      }
    }
  }
}

// ============================================================================
// Column-ownership persistent GRU + fused logits.
//   blocks [0,16):  layer 0, block q owns H-cols [q*32, q*32+32)
//   blocks [16,48): layer 1, block q owns H-cols [q*16, q*16+16)
//   blocks [48,256): logits workers (hb1 slots as published)
// Per stage s: RU phase (gates GEMM; u,r in regs; publish rh slice) ; gbar ;
//              C phase (c GEMM over published rh; h update in regs; publish
//              hb slice) ; gbar.  u/h NEVER leave the block.
// ============================================================================
struct PArgs {
  const bf16_t *Btru0, *Bt1ru, *Btc0, *Btc1;
  const float  *xg0, *bu, *br, *bc, *hs0init;
  bf16_t *hb0_seq, *hb1_seq, *rh0s, *rh1s;
  const bf16_t *Wto;
  const float  *bo;
  float *out, *out_hfin;
  unsigned *sync;
};

// GEMM over K with NF 16-col output fragments; B staged in LDS (swizzled,
// row stride 2*K bytes); A panels plain-cached row-major [128][512] bf16.
template<int K, int NF>
__device__ __forceinline__ void tile_gemm(
    const bf16_t* __restrict__ A0, const bf16_t* __restrict__ A1,
    const bf16_t* Bs, int wave, int lane, f32x4 (&acc)[2][4])
{
  const int l15 = lane & 15, kg = lane >> 4;
  const int mw = wave * 32;
#pragma unroll
  for (int i = 0; i < 2; ++i)
#pragma unroll
    for (int f = 0; f < NF; ++f)
#pragma unroll
      for (int e = 0; e < 4; ++e) acc[i][f][e] = 0.f;

#pragma unroll
  for (int kk = 0; kk < K; kk += 32) {
    const bf16_t* Asrc = (kk < 512) ? A0 : A1;
    const int kc = (kk < 512 ? kk : kk - 512) + kg * 8;
    bf16x8 a[2];
#pragma unroll
    for (int i = 0; i < 2; ++i)
      a[i] = *(const bf16x8*)(Asrc + (size_t)(mw + i * 16 + l15) * 512 + kc);
    bf16x8 b[NF];
#pragma unroll
    for (int f = 0; f < NF; ++f) {
      int row = f * 16 + l15;
      int byteoff = row * (2 * K) + ((2 * kk + 16 * kg) ^ ((row & 7) << 4));
      b[f] = *(const bf16x8*)((const char*)Bs + byteoff);
    }
#pragma unroll
    for (int i = 0; i < 2; ++i)
#pragma unroll
      for (int f = 0; f < NF; ++f)
        acc[i][f] = __builtin_amdgcn_mfma_f32_16x16x32_bf16(a[i], b[f], acc[i][f], 0, 0, 0);
  }
}

// Publish C cols (C=32 or 16) of a 128-row fragment set as bf16 into a
// row-major [128][512] slice at col n0: fragment->LDS transpose->coalesced
// agent u64 stores.
template<int C>
__device__ __forceinline__ void publish(
    bf16_t* dst, int n0, float (&v)[2][2][4],
    unsigned short (*tb)[36], int wave, int lane, int tid)
{
  const int l15 = lane & 15, kg = lane >> 4;
  const int mw = wave * 32;
  constexpr int NFp = C / 16;
#pragma unroll
  for (int i = 0; i < 2; ++i)
#pragma unroll
    for (int f = 0; f < NFp; ++f)
#pragma unroll
      for (int e = 0; e < 4; ++e)
        tb[mw + i * 16 + kg * 4 + e][f * 16 + l15] =
            __builtin_bit_cast(unsigned short, (bf16_t)v[i][f][e]);
  __syncthreads();
  constexpr int NU = 128 * C / 4;       // u64 count
  constexpr int IT = NU / 256;
#pragma unroll
  for (int it = 0; it < IT; ++it) {
    int lin = it * 256 + tid;
    int row = lin / (C / 4);
    int cc  = (lin % (C / 4)) * 4;
    u16x4 pk = { tb[row][cc], tb[row][cc + 1], tb[row][cc + 2], tb[row][cc + 3] };
    cst64(dst + (size_t)row * 512 + n0 + cc, __builtin_bit_cast(u64, pk));
  }
}

__global__ __launch_bounds__(256) void gru_persist(PArgs P)
{
  const int bid = blockIdx.x, tid = threadIdx.x;
  const int wave = tid >> 6, lane = tid & 63;
  const int l15 = lane & 15, kg = lane >> 4;
  const int mw = wave * 32;
  unsigned* sync = P.sync;

  // One-time per-block L2/L1 invalidate (stale clean-line protocol, R12).
  __threadfence();
  __syncthreads();

  // ===================== logits worker blocks =====================
  if (bid >= NBLK) {
    const int w = bid - NBLK;                 // 0..207
    const int wm = (wave >> 1) * 64, wn = (wave & 1) * 64;
    unsigned* gen = sync + (9 + (w & 7)) * 64;
    for (int tau = w; tau < TT * 79; tau += (NGRID - NBLK)) {
      const int t = tau / 79, nb = tau % 79;
      if (tid == 0) {
        const unsigned need = (unsigned)(2 * t + 4);
        while (__hip_atomic_load(gen, __ATOMIC_RELAXED,
                                 __HIP_MEMORY_SCOPE_AGENT) < need)
          __builtin_amdgcn_s_sleep(32);
      }
      asm volatile("" ::: "memory");
      __syncthreads();
      const bf16_t* A = P.hb1_seq + (size_t)(t + 1) * SLOT;
      const bf16_t* Bp = P.Wto + (size_t)(nb * 128 + wn + l15) * 512 + kg * 8;
      f32x4 acc[4][4];
#pragma unroll
      for (int i = 0; i < 4; ++i)
#pragma unroll
        for (int j = 0; j < 4; ++j)
#pragma unroll
          for (int e = 0; e < 4; ++e) acc[i][j][e] = 0.f;
      for (int kk = 0; kk < 512; kk += 32) {
        bf16x8 a[4], b[4];
#pragma unroll
        for (int i = 0; i < 4; ++i)
          a[i] = *(const bf16x8*)(A + (size_t)(wm + i * 16 + l15) * 512 + kk + kg * 8);
#pragma unroll
        for (int j = 0; j < 4; ++j)
          b[j] = *(const bf16x8*)(Bp + (size_t)j * 16 * 512 + kk);
#pragma unroll
        for (int i = 0; i < 4; ++i)
#pragma unroll
          for (int j = 0; j < 4; ++j)
            acc[i][j] = __builtin_amdgcn_mfma_f32_16x16x32_bf16(a[i], b[j], acc[i][j], 0, 0, 0);
      }
#pragma unroll
      for (int fm = 0; fm < 4; ++fm) {
#pragma unroll
        for (int fn = 0; fn < 4; ++fn) {
          int n = nb * 128 + wn + fn * 16 + l15;
          if (n >= VV) continue;
          float bv = P.bo[n];
#pragma unroll
          for (int e = 0; e < 4; ++e) {
            int b_row = wm + fm * 16 + kg * 4 + e;
            P.out[(size_t)(b_row * TT + t) * VV + n] = acc[fm][fn][e] + bv;
          }
        }
      }
      __syncthreads();
    }
    return;
  }

  // ===================== recurrence blocks (column-ownership) =============
  const bool L0 = (bid < 16);
  const int q  = L0 ? bid : bid - 16;
  const int n0 = L0 ? q * 32 : q * 16;   // owned H-col base

  // LDS: staged weights (96 KB) + publish transpose scratch (9 KB)
  __shared__ bf16_t Bs[49152];                  // [RU 64KB | C 32KB]
  __shared__ unsigned short tb[128][36];
  bf16_t* BsRU = Bs;
  bf16_t* BsC  = Bs + 32768;

  // ---- stage weights (swizzled) ----
  if (L0) {
    // BsRU: 64 rows x 1024B: rows 0-31 = Btru0[n0+j] (u), 32-63 = Btru0[512+n0+j-32] (r)
    for (int c = tid; c < 4096; c += 256) {
      int row = c >> 6, cb = (c & 63) * 16;
      const bf16_t* src = (row < 32) ? P.Btru0 + (size_t)(n0 + row) * 512
                                     : P.Btru0 + (size_t)(512 + n0 + row - 32) * 512;
      *(f4*)((char*)BsRU + row * 1024 + (cb ^ ((row & 7) << 4))) =
          *(const f4*)((const char*)src + cb);
    }
    // BsC: 32 rows x 1024B: Btc0[n0+j]
    for (int c = tid; c < 2048; c += 256) {
      int row = c >> 6, cb = (c & 63) * 16;
      const bf16_t* src = P.Btc0 + (size_t)(n0 + row) * 512;
      *(f4*)((char*)BsC + row * 1024 + (cb ^ ((row & 7) << 4))) =
          *(const f4*)((const char*)src + cb);
    }
  } else {
    // BsRU: 32 rows x 2048B: rows 0-15 = Bt1ru[n0+j] (u), 16-31 = Bt1ru[512+n0+j-16] (r)
    for (int c = tid; c < 4096; c += 256) {
      int row = c >> 7, cb = (c & 127) * 16;
      const bf16_t* src = (row < 16) ? P.Bt1ru + (size_t)(n0 + row) * 1024
                                     : P.Bt1ru + (size_t)(512 + n0 + row - 16) * 1024;
      *(f4*)((char*)BsRU + row * 2048 + (cb ^ ((row & 7) << 4))) =
          *(const f4*)((const char*)src + cb);
    }
    // BsC: 16 rows x 2048B: Btc1[n0+j]
    for (int c = tid; c < 2048; c += 256) {
      int row = c >> 7, cb = (c & 127) * 16;
      const bf16_t* src = P.Btc1 + (size_t)(n0 + row) * 1024;
      *(f4*)((char*)BsC + row * 2048 + (cb ^ ((row & 7) << 4))) =
          *(const f4*)((const char*)src + cb);
    }
  }
  __syncthreads();

  // ---- register state: h (fp32) for owned cols; u held between phases ----
  const int NFh = L0 ? 2 : 1;
  float hreg[2][2][4], ureg[2][2][4], rhv[2][2][4];
#pragma unroll
  for (int i = 0; i < 2; ++i)
    for (int f = 0; f < 2; ++f)
#pragma unroll
      for (int e = 0; e < 4; ++e) {
        int row = mw + i * 16 + kg * 4 + e;
        hreg[i][f][e] = (f < NFh)
            ? P.hs0init[(size_t)row * 512 + n0 + f * 16 + l15] : 0.f;
        ureg[i][f][e] = 0.f; rhv[i][f][e] = 0.f;
      }

  for (int s = 0; s <= 40; ++s) {
    // ---------------- phase RU ----------------
    if (L0 && s < 40) {
      f32x4 acc[2][4];
      const bf16_t* A0 = P.hb0_seq + (size_t)s * SLOT;
      tile_gemm<512, 4>(A0, A0, BsRU, wave, lane, acc);
      const float* xg = P.xg0 + (size_t)s * 128 * 1536;
#pragma unroll
      for (int i = 0; i < 2; ++i)
#pragma unroll
        for (int f = 0; f < 2; ++f)
#pragma unroll
          for (int e = 0; e < 4; ++e) {
            int row = mw + i * 16 + kg * 4 + e;
            int col = n0 + f * 16 + l15;
            float pu = acc[i][f][e]     + xg[(size_t)row * 1536 + col];
            float pr = acc[i][f + 2][e] + xg[(size_t)row * 1536 + 512 + col];
            ureg[i][f][e] = 1.f / (1.f + expf(-pu));
            rhv[i][f][e]  = (1.f / (1.f + expf(-pr))) * hreg[i][f][e];
          }
      publish<32>(P.rh0s + (size_t)s * SLOT, n0, rhv, tb, wave, lane, tid);
    } else if (!L0 && s >= 1) {
      f32x4 acc[2][4];
      tile_gemm<1024, 2>(P.hb0_seq + (size_t)s * SLOT,
                         P.hb1_seq + (size_t)(s - 1) * SLOT,
                         BsRU, wave, lane, acc);
      float bvu = P.bu[512 + n0 + l15];
      float bvr = P.br[512 + n0 + l15];
#pragma unroll
      for (int i = 0; i < 2; ++i)
#pragma unroll
        for (int e = 0; e < 4; ++e) {
          float pu = acc[i][0][e] + bvu;
          float pr = acc[i][1][e] + bvr;
          ureg[i][0][e] = 1.f / (1.f + expf(-pu));
          rhv[i][0][e]  = (1.f / (1.f + expf(-pr))) * hreg[i][0][e];
        }
      publish<16>(P.rh1s + (size_t)s * SLOT, n0, rhv, tb, wave, lane, tid);
    }
    gbar(sync, 2 * s);
    // ---------------- phase C ----------------
    if (L0 && s < 40) {
      f32x4 acc[2][4];
      const bf16_t* Arh = P.rh0s + (size_t)s * SLOT;
      tile_gemm<512, 2>(Arh, Arh, BsC, wave, lane, acc);
      const float* xg = P.xg0 + (size_t)s * 128 * 1536;
#pragma unroll
      for (int i = 0; i < 2; ++i)
#pragma unroll
        for (int f = 0; f < 2; ++f)
#pragma unroll
          for (int e = 0; e < 4; ++e) {
            int row = mw + i * 16 + kg * 4 + e;
            int col = n0 + f * 16 + l15;
            float c = tanhf(acc[i][f][e] + xg[(size_t)row * 1536 + 1024 + col]);
            float u = ureg[i][f][e];
            hreg[i][f][e] = u * hreg[i][f][e] + (1.f - u) * c;
            rhv[i][f][e] = hreg[i][f][e];    // reuse as publish staging
          }
      publish<32>(P.hb0_seq + (size_t)(s + 1) * SLOT, n0, rhv, tb, wave, lane, tid);
    } else if (!L0 && s >= 1) {
      f32x4 acc[2][4];
      tile_gemm<1024, 1>(P.hb0_seq + (size_t)s * SLOT,
                         P.rh1s + (size_t)s * SLOT,
                         BsC, wave, lane, acc);
      float bvc = P.bc[512 + n0 + l15];
#pragma unroll
      for (int i = 0; i < 2; ++i)
#pragma unroll
        for (int e = 0; e < 4; ++e) {
          float c = tanhf(acc[i][0][e] + bvc);
          float u = ureg[i][0][e];
          hreg[i][0][e] = u * hreg[i][0][e] + (1.f - u) * c;
          rhv[i][0][e] = hreg[i][0][e];
        }
      publish<16>(P.hb1_seq + (size_t)s * SLOT, n0, rhv, tb, wave, lane, tid);
    }
    gbar(sync, 2 * s + 1);
  }

  // ---- h_final [L,B,H]: owner blocks write their fp32 column slices ----
  float* dst = P.out_hfin + (L0 ? 0 : 65536);
#pragma unroll
  for (int i = 0; i < 2; ++i)
    for (int f = 0; f < NFh; ++f)
#pragma unroll
      for (int e = 0; e < 4; ++e) {
        int row = mw + i * 16 + kg * 4 + e;
        dst[(size_t)row * 512 + n0 + f * 16 + l15] = hreg[i][f][e];
      }
}

// ============================================================================
// h0 = tanh(vgg @ W_in + b_in) via bf16 MFMA, split-K=8.
// ============================================================================
__global__ __launch_bounds__(256) void h0_gemm(
    const bf16_t* __restrict__ vggb, const bf16_t* __restrict__ Wint,
    float* __restrict__ part)
{
  const int bn = blockIdx.x * 128, z = blockIdx.y, k0 = z * 512;
  const int tid = threadIdx.x;
  const int wave = tid >> 6, lane = tid & 63;
  const int wm = (wave >> 1) * 64, wn = (wave & 1) * 64;
  const int l15 = lane & 15, kg = lane >> 4;
  const bf16_t* Ap = vggb + (size_t)(wm + l15) * 4096 + k0 + kg * 8;
  const bf16_t* Bp = Wint + (size_t)(bn + wn + l15) * 4096 + k0 + kg * 8;
  f32x4 acc[4][4];
#pragma unroll
  for (int i = 0; i < 4; ++i)
#pragma unroll
    for (int j = 0; j < 4; ++j)
#pragma unroll
      for (int e = 0; e < 4; ++e) acc[i][j][e] = 0.f;
  for (int kk = 0; kk < 512; kk += 32) {
    bf16x8 a[4], b[4];
#pragma unroll
    for (int i = 0; i < 4; ++i) a[i] = *(const bf16x8*)(Ap + (size_t)i * 16 * 4096 + kk);
#pragma unroll
    for (int j = 0; j < 4; ++j) b[j] = *(const bf16x8*)(Bp + (size_t)j * 16 * 4096 + kk);
#pragma unroll
    for (int i = 0; i < 4; ++i)
#pragma unroll
      for (int j = 0; j < 4; ++j)
        acc[i][j] = __builtin_amdgcn_mfma_f32_16x16x32_bf16(a[i], b[j], acc[i][j], 0, 0, 0);
  }
#pragma unroll
  for (int fm = 0; fm < 4; ++fm)
#pragma unroll
    for (int fn = 0; fn < 4; ++fn) {
      int n = bn + wn + fn * 16 + l15;
#pragma unroll
      for (int e = 0; e < 4; ++e) {
        int m = wm + fm * 16 + kg * 4 + e;
        part[(size_t)z * SLOT + m * 512 + n] = acc[fm][fn][e];
      }
    }
}

__global__ void h0_fin(const float* __restrict__ part, const float* __restrict__ bin,
                       float* __restrict__ hs0init,
                       bf16_t* __restrict__ hb00, bf16_t* __restrict__ hb10)
{
  int i = blockIdx.x * 256 + threadIdx.x;   // 65536
  int n = i & 511;
  float s = bin[n];
#pragma unroll
  for (int z = 0; z < 8; ++z) s += part[(size_t)z * SLOT + i];
  float v = tanhf(s);
  hs0init[i] = v;
  hb00[i] = (bf16_t)v; hb10[i] = (bf16_t)v;
}

__global__ void conv_bf16(const float* __restrict__ src, bf16_t* __restrict__ dst)
{
  int i = blockIdx.x * 256 + threadIdx.x;
  f4 v = ((const f4*)src)[i];
  dst[i * 4 + 0] = (bf16_t)v[0]; dst[i * 4 + 1] = (bf16_t)v[1];
  dst[i * 4 + 2] = (bf16_t)v[2]; dst[i * 4 + 3] = (bf16_t)v[3];
}

__global__ void gather_emb(const int* __restrict__ tok, const float* __restrict__ emb,
                           bf16_t* __restrict__ A)
{
  int m = blockIdx.x;
  int t = m >> 7, b = m & 127;
  int tk = tok[b * TT + t];
  const float* src = emb + (size_t)tk * 512;
  int i = threadIdx.x;
  f4 v = *(const f4*)(src + i * 4);
  bf16_t* dst = A + (size_t)m * 512 + i * 4;
  dst[0] = (bf16_t)v[0]; dst[1] = (bf16_t)v[1];
  dst[2] = (bf16_t)v[2]; dst[3] = (bf16_t)v[3];
}

struct TJob { const float* src; bf16_t* dst; int K; int dstld; };
struct TJobs10 { TJob j[10]; };
__global__ void transpose_gen(TJobs10 jobs)
{
  TJob jb = jobs.j[blockIdx.z];
  int k0 = blockIdx.x * 32;
  if (k0 >= jb.K) return;
  int n0 = blockIdx.y * 32;
  __shared__ float tile[32][33];
  int tx = threadIdx.x, ty = threadIdx.y;
#pragma unroll
  for (int r = 0; r < 4; ++r)
    tile[ty + 8 * r][tx] = jb.src[(size_t)(k0 + ty + 8 * r) * 512 + n0 + tx];
  __syncthreads();
#pragma unroll
  for (int r = 0; r < 4; ++r)
    jb.dst[(size_t)(n0 + ty + 8 * r) * jb.dstld + k0 + tx] = (bf16_t)tile[tx][ty + 8 * r];
}

__global__ void transpose_wout(const float* __restrict__ W, bf16_t* __restrict__ dst)
{
  __shared__ float tile[32][33];
  int k0 = blockIdx.x * 32, n0 = blockIdx.y * 32;
  int tx = threadIdx.x, ty = threadIdx.y;
#pragma unroll
  for (int r = 0; r < 4; ++r) {
    int n = n0 + tx;
    tile[ty + 8 * r][tx] = (n < VV) ? W[(size_t)(k0 + ty + 8 * r) * VV + n] : 0.f;
  }
  __syncthreads();
#pragma unroll
  for (int r = 0; r < 4; ++r)
    dst[(size_t)(n0 + ty + 8 * r) * 512 + k0 + tx] = (bf16_t)tile[tx][ty + 8 * r];
}

__global__ void build_xbias(const float* __restrict__ bu, const float* __restrict__ br,
                            const float* __restrict__ bc, float* __restrict__ xb)
{
  int i = blockIdx.x * 256 + threadIdx.x;
  if (i < 2 * 1536) {
    int j = i / 1536, qq = i % 1536;
    int g = qq >> 9, n = qq & 511;
    const float* src = (g == 0) ? bu : (g == 1) ? br : bc;
    xb[i] = src[j * 512 + n];
  }
}

// ============================================================================
extern "C" void kernel_launch(void* const* d_in, const int* in_sizes, int n_in,
                              void* d_out, int out_size, void* d_ws, size_t ws_size,
                              hipStream_t stream)
{
  const int*   tok = (const int*)  d_in[0];
  const float* vgg = (const float*)d_in[1];
  const float* emb = (const float*)d_in[2];
  const float* Win = (const float*)d_in[3];
  const float* bin = (const float*)d_in[4];
  const float* Wu  = (const float*)d_in[5];
  const float* bu  = (const float*)d_in[6];
  const float* Wr  = (const float*)d_in[7];
  const float* br  = (const float*)d_in[8];
  const float* Wc  = (const float*)d_in[9];
  const float* bc  = (const float*)d_in[10];
  const float* Wo  = (const float*)d_in[11];
  const float* bo  = (const float*)d_in[12];
  float* out = (float*)d_out;

  size_t off = 0;
  auto alloc = [&](size_t bytes) -> void* {
    void* p = (char*)d_ws + off;
    off += (bytes + 255) & ~(size_t)255;
    return p;
  };
  float*  hs0init = (float*) alloc(SLOT * 4);
  bf16_t* rh0s  = (bf16_t*)alloc(41 * SLOT * 2);
  bf16_t* rh1s  = (bf16_t*)alloc(41 * SLOT * 2);
  bf16_t* hb0_seq = (bf16_t*)alloc(41 * SLOT * 2);
  bf16_t* hb1_seq = (bf16_t*)alloc(41 * SLOT * 2);
  bf16_t* Aemb  = (bf16_t*)alloc((size_t)TT * BB * 512 * 2);
  float*  xg0   = (float*) alloc((size_t)TT * BB * 1536 * 4);
  bf16_t* Btx0  = (bf16_t*)alloc((size_t)1536 * 512 * 2);
  bf16_t* Btru0 = (bf16_t*)alloc((size_t)1024 * 512 * 2);
  bf16_t* Btc0  = (bf16_t*)alloc((size_t)512 * 512 * 2);
  bf16_t* Bt1ru = (bf16_t*)alloc((size_t)1024 * 1024 * 2);
  bf16_t* Btc1  = (bf16_t*)alloc((size_t)512 * 1024 * 2);
  bf16_t* Wto   = (bf16_t*)alloc((size_t)10112 * 512 * 2);
  bf16_t* Wint  = (bf16_t*)alloc((size_t)512 * 4096 * 2);
  bf16_t* vggb  = (bf16_t*)alloc((size_t)128 * 4096 * 2);
  float*  h0part= (float*) alloc(8 * SLOT * 4);
  float*  xbias = (float*) alloc(2 * 1536 * 4);
  unsigned* syncws = (unsigned*) alloc(8192);
  if (off > ws_size) return;

  TJobs10 tj;
  tj.j[0] = { Wu,                Btx0,                512, 512 };
  tj.j[1] = { Wr,                Btx0 + 262144,       512, 512 };
  tj.j[2] = { Wc,                Btx0 + 524288,       512, 512 };
  tj.j[3] = { Wu + 262144,       Btru0,               512, 512 };
  tj.j[4] = { Wr + 262144,       Btru0 + 262144,      512, 512 };
  tj.j[5] = { Wc + 262144,       Btc0,                512, 512 };
  tj.j[6] = { Wu + 524288,       Bt1ru,               1024, 1024 };
  tj.j[7] = { Wr + 524288,       Bt1ru + 524288,      1024, 1024 };
  tj.j[8] = { Wc + 524288,       Btc1,                1024, 1024 };
  tj.j[9] = { Win,               Wint,                4096, 4096 };
  transpose_gen<<<dim3(128, 16, 10), dim3(32, 8), 0, stream>>>(tj);
  transpose_wout<<<dim3(16, 316), dim3(32, 8), 0, stream>>>(Wo, Wto);
  build_xbias<<<12, 256, 0, stream>>>(bu, br, bc, xbias);
  gather_emb<<<TT * BB, 128, 0, stream>>>(tok, emb, Aemb);
  conv_bf16<<<512, 256, 0, stream>>>(vgg, vggb);
  zero_sync<<<1, 256, 0, stream>>>(syncws);

  h0_gemm<<<dim3(4, 8), 256, 0, stream>>>(vggb, Wint, h0part);
  h0_fin<<<256, 256, 0, stream>>>(h0part, bin, hs0init, hb0_seq, hb1_seq);

  gemm_bt<<<dim3(40, 12), 256, 0, stream>>>(Aemb, Btx0, xbias, xg0, 1536, 1536, 0);

  PArgs pa;
  pa.Btru0 = Btru0; pa.Bt1ru = Bt1ru; pa.Btc0 = Btc0; pa.Btc1 = Btc1;
  pa.xg0 = xg0; pa.bu = bu; pa.br = br; pa.bc = bc; pa.hs0init = hs0init;
  pa.hb0_seq = hb0_seq; pa.hb1_seq = hb1_seq;
  pa.rh0s = rh0s; pa.rh1s = rh1s;
  pa.Wto = Wto; pa.bo = bo; pa.out = out;
  pa.out_hfin = out + (size_t)BB * TT * VV;
  pa.sync = syncws;
  gru_persist<<<NGRID, 256, 0, stream>>>(pa);
}